// Round 13
// baseline (395.266 us; speedup 1.0000x reference)
//
#include <hip/hip_runtime.h>

#define NNODES 50000
#define NEDGES 200000
#define DD 128
#define LN_EPS 1e-5f
#define NTH 256

typedef __attribute__((ext_vector_type(8))) short bf16x8;
typedef __attribute__((ext_vector_type(4))) float f32x4;
typedef __attribute__((ext_vector_type(16))) float f32x16;

template<int N> struct ic { static constexpr int value = N; };

__device__ __forceinline__ unsigned short bfr(float f) {
    union { float f; unsigned u; } v; v.f = f;
    return (unsigned short)((v.u + 0x7fffu + ((v.u >> 16) & 1u)) >> 16);
}
__device__ __forceinline__ unsigned pk2(float a, float b) {
    return (unsigned)bfr(a) | ((unsigned)bfr(b) << 16);
}
__device__ __forceinline__ void gload_lds16(const void* g, void* l) {
    __builtin_amdgcn_global_load_lds(
        (const __attribute__((address_space(1))) void*)g,
        (__attribute__((address_space(3))) void*)l, 16, 0, 0);
}

// ---------------------------------------------------------------------------
// Fused pre-pass: blocks [0,72)  -> weight image builder (r6-proven layout)
//                 blocks [72, +1024) -> nodef bf16 mirror + receiver histogram
// Weight image per k32 chunk c (8 KB): granule(nt, n32, ks):
//   byte = c*8192 + nt*2048 + n32*64 + ((ks ^ ((n32 + (n32>>2)) & 3)) << 4)
//   content: Wt[n = nt*32+n32][k = c*32 + ks*8 + e], e=0..7 (bf16)
// ---------------------------------------------------------------------------
__global__ __launch_bounds__(NTH)
void prepass(const float* __restrict__ We1, const float* __restrict__ We2,
             const float* __restrict__ We3, const float* __restrict__ Wn1,
             const float* __restrict__ Wn2, const float* __restrict__ Wn3,
             char* __restrict__ img_e, char* __restrict__ img_n,
             const float* __restrict__ nodef, const int* __restrict__ recv,
             uint4* __restrict__ nodb, int* __restrict__ cnt) {
    if (blockIdx.x < 72) {
        int tid = blockIdx.x * NTH + threadIdx.x;
        const float* W; char* dst; int q;
        if      (tid <  6144) { W = We1; dst = img_e;             q = tid;         }
        else if (tid <  8192) { W = We2; dst = img_e + 12 * 8192; q = tid - 6144;  }
        else if (tid < 10240) { W = We3; dst = img_e + 16 * 8192; q = tid - 8192;  }
        else if (tid < 14336) { W = Wn1; dst = img_n;             q = tid - 10240; }
        else if (tid < 16384) { W = Wn2; dst = img_n + 8 * 8192;  q = tid - 14336; }
        else if (tid < 18432) { W = Wn3; dst = img_n + 12 * 8192; q = tid - 16384; }
        else return;
        int c = q >> 9, rem = q & 511;
        int nt = rem >> 7, r2 = rem & 127, n32 = r2 >> 2, ks = r2 & 3;
        int n = nt * 32 + n32;
        int sx = (n32 + (n32 >> 2)) & 3;
        int k0 = c * 32 + ks * 8;
        unsigned short o[8];
        #pragma unroll
        for (int e = 0; e < 8; ++e)
            o[e] = bfr(W[(size_t)(k0 + e) * DD + n]);
        uint4 val;
        val.x = (unsigned)o[0] | ((unsigned)o[1] << 16);
        val.y = (unsigned)o[2] | ((unsigned)o[3] << 16);
        val.z = (unsigned)o[4] | ((unsigned)o[5] << 16);
        val.w = (unsigned)o[6] | ((unsigned)o[7] << 16);
        *(uint4*)(dst + (size_t)c * 8192 + nt * 2048 + n32 * 64 + ((ks ^ sx) << 4)) = val;
    } else {
        const int b = blockIdx.x - 72;
        const int tid0 = b * NTH + threadIdx.x;
        if (tid0 < NEDGES) atomicAdd(&cnt[recv[tid0]], 1);
        const int NG = NNODES * 16;
        for (int g = tid0; g < NG; g += 1024 * NTH) {
            f32x4 a = ((const f32x4*)nodef)[g * 2];
            f32x4 bb = ((const f32x4*)nodef)[g * 2 + 1];
            uint4 o;
            o.x = pk2(a[0], a[1]); o.y = pk2(a[2], a[3]);
            o.z = pk2(bb[0], bb[1]); o.w = pk2(bb[2], bb[3]);
            nodb[g] = o;
        }
    }
}

// ---------------------------------------------------------------------------
// CSR: 2-level scan + fill (stores perm[e] = CSR position of edge e)
// ---------------------------------------------------------------------------
__global__ __launch_bounds__(NTH)
void csr_scan1(const int* __restrict__ cnt, int* __restrict__ part) {
    __shared__ int red[NTH];
    const int b = blockIdx.x, t = threadIdx.x;
    const int base = b * 196;
    int s = 0;
    for (int i = t; i < 196; i += NTH) {
        int idx = base + i;
        if (idx < NNODES) s += cnt[idx];
    }
    red[t] = s;
    __syncthreads();
    for (int d = NTH / 2; d > 0; d >>= 1) {
        if (t < d) red[t] += red[t + d];
        __syncthreads();
    }
    if (t == 0) part[b] = red[0];
}

__global__ __launch_bounds__(NTH)
void csr_scan2(const int* __restrict__ cnt, const int* __restrict__ part,
               int* __restrict__ off, int* __restrict__ cursor) {
    __shared__ int sp[NTH];
    const int t = threadIdx.x;
    sp[t] = part[t];
    __syncthreads();
    for (int d = 1; d < NTH; d <<= 1) {
        int v = (t >= d) ? sp[t - d] : 0;
        __syncthreads();
        sp[t] += v;
        __syncthreads();
    }
    int run = (t == 0) ? 0 : sp[t - 1];
    const int base = t * 196;
    for (int i = 0; i < 196; ++i) {
        int idx = base + i;
        if (idx < NNODES) { off[idx] = run; cursor[idx] = run; run += cnt[idx]; }
    }
    if (t == NTH - 1) off[NNODES] = NEDGES;
}

__global__ void csr_fill(const int* __restrict__ recv, int* __restrict__ cursor,
                         int* __restrict__ perm) {
    int e = blockIdx.x * NTH + threadIdx.x;
    if (e < NEDGES) {
        int p = atomicAdd(&cursor[recv[e]], 1);
        perm[e] = p;
    }
}

// ---------------------------------------------------------------------------
// Aggregate (bf16): ybuf is CSR-ordered -> pure streaming reads.
// ---------------------------------------------------------------------------
__global__ __launch_bounds__(NTH)
void aggregate(const unsigned* __restrict__ ybuf,
               const int* __restrict__ off,
               unsigned* __restrict__ aggb) {
    const int n = blockIdx.x * 4 + (threadIdx.x >> 6);
    const int l = threadIdx.x & 63;
    if (n >= NNODES) return;
    const int j0 = off[n], j1 = off[n + 1];
    float sx = 0.f, sy = 0.f;
    int j = j0;
    for (; j + 4 <= j1; j += 4) {
        unsigned v0 = ybuf[(size_t)j * 64 + l];
        unsigned v1 = ybuf[(size_t)(j + 1) * 64 + l];
        unsigned v2 = ybuf[(size_t)(j + 2) * 64 + l];
        unsigned v3 = ybuf[(size_t)(j + 3) * 64 + l];
        sx += __uint_as_float(v0 << 16) + __uint_as_float(v1 << 16)
            + __uint_as_float(v2 << 16) + __uint_as_float(v3 << 16);
        sy += __uint_as_float(v0 & 0xffff0000u) + __uint_as_float(v1 & 0xffff0000u)
            + __uint_as_float(v2 & 0xffff0000u) + __uint_as_float(v3 & 0xffff0000u);
    }
    for (; j < j1; ++j) {
        unsigned v = ybuf[(size_t)j * 64 + l];
        sx += __uint_as_float(v << 16);
        sy += __uint_as_float(v & 0xffff0000u);
    }
    aggb[(size_t)n * 64 + l] = pk2(sx, sy);
}

// ---------------------------------------------------------------------------
// Fused MLP, 32x32x16 MFMA (r11-proven order + vmcnt tables).
// CHANGE vs r11: H1/H2 entirely in registers (hfr[8], one shfl_xor(32) per
// packed u32; own group 2kh+hi, send group 2kh+1-hi -- lane-table verified).
// Hb deleted -> LDS = 40 KB -> 4 blocks/CU (2x concurrent barrier groups).
// ---------------------------------------------------------------------------
template<int MODE>
__global__ __launch_bounds__(NTH, 4)
void mgn_mfma(const float* __restrict__ nodef, const float* __restrict__ edgef,
              const unsigned short* __restrict__ nodb,
              const int* __restrict__ senders, const int* __restrict__ receivers,
              const int* __restrict__ perm,
              const char* __restrict__ img,
              const float* __restrict__ b1, const float* __restrict__ b2,
              const float* __restrict__ b3,
              const float* __restrict__ gamma, const float* __restrict__ beta,
              const unsigned short* __restrict__ aggb, unsigned* __restrict__ ybuf,
              float* __restrict__ outp)
{
    __shared__ char Wbuf[5 * 8192];   // 5 rotating k32 weight chunks (40 KB)

    const int t  = threadIdx.x;
    const int w  = t >> 6;
    const int l  = t & 63;
    const int ln = l & 31;
    const int hi = l >> 5;
    const int row0 = blockIdx.x * 128;
    const int gm = row0 + w * 32 + ln;
    constexpr int NROWS = (MODE == 0) ? NEDGES : NNODES;
    constexpr int NK1   = (MODE == 0) ? 12 : 8;
    constexpr int NCH   = NK1 + 8;
    const int gmc = gm < NROWS ? gm : NROWS - 1;
    const int sxA = (ln + (ln >> 2)) & 3;

    int srow = 0, rrow = 0, prow = 0;
    if (MODE == 0) { srow = senders[gmc]; rrow = receivers[gmc]; prow = perm[gmc]; }

    const f32x16 fz = {0.f,0.f,0.f,0.f,0.f,0.f,0.f,0.f,
                       0.f,0.f,0.f,0.f,0.f,0.f,0.f,0.f};
    f32x16 acc[4];
    #pragma unroll
    for (int nt = 0; nt < 4; ++nt) acc[nt] = fz;

    bf16x8 bS[3][2];   // bf16 B rotation, lead 2
    f32x4  fS[3][4];   // fp32 B rotation (edge chunks 8..11), lead 2
    bf16x8 hfr[8];     // H fragments in registers: [kc*2 + kh]

    auto stageW = [&](int c) {
        const char* src = img + (size_t)c * 8192 + t * 16;
        char* dstl = Wbuf + (c % 5) * 8192 + t * 16;
        gload_lds16(src, dstl);
        gload_lds16(src + 4096, dstl + 4096);
    };

    auto loadBB = [&](auto CC, bf16x8* dst) {
        constexpr int c = decltype(CC)::value;
        const unsigned short* base;
        if constexpr (MODE == 0) {
            base = (c < 4) ? nodb + (size_t)srow * DD : nodb + (size_t)rrow * DD;
        } else {
            base = (c < 4) ? nodb + (size_t)gmc * DD : aggb + (size_t)gmc * DD;
        }
        const char* p = (const char*)base + (c & 3) * 64 + hi * 16;
        dst[0] = *(const bf16x8*)p;
        dst[1] = *(const bf16x8*)(p + 32);
    };

    auto loadBF = [&](auto CC, f32x4* dst) {
        constexpr int c = decltype(CC)::value;
        const float* p = edgef + (size_t)gmc * DD + (c & 3) * 32 + hi * 8;
        dst[0] = *(const f32x4*)p;
        dst[1] = *(const f32x4*)(p + 4);
        dst[2] = *(const f32x4*)(p + 16);
        dst[3] = *(const f32x4*)(p + 20);
    };

    auto cvtB = [&](const f32x4* br) {
        union { unsigned u[4]; bf16x8 v; } r;
        r.u[0] = pk2(br[0][0], br[0][1]);
        r.u[1] = pk2(br[0][2], br[0][3]);
        r.u[2] = pk2(br[1][0], br[1][1]);
        r.u[3] = pk2(br[1][2], br[1][3]);
        return r.v;
    };

    auto getB = [&](auto CC, int kh) -> bf16x8 {
        constexpr int c = decltype(CC)::value;
        if constexpr (c >= NK1) {
            return hfr[((c - NK1) & 3) * 2 + kh];
        } else if constexpr (MODE == 0 && c >= 8) {
            return cvtB(&fS[c % 3][kh * 2]);
        } else {
            return bS[c % 3][kh];
        }
    };

    auto compute = [&](auto CC) {
        constexpr int c = decltype(CC)::value;
        const char* bp = Wbuf + (c % 5) * 8192 + ln * 64;
        #pragma unroll
        for (int kh = 0; kh < 2; ++kh) {
            bf16x8 b = getB(CC, kh);
            #pragma unroll
            for (int nt = 0; nt < 4; ++nt) {
                bf16x8 a = *(const bf16x8*)(bp + nt * 2048
                            + (((kh * 2 + hi) ^ sxA) << 4));
                acc[nt] = __builtin_amdgcn_mfma_f32_32x32x16_bf16(a, b, acc[nt], 0, 0, 0);
            }
        }
    };

    // ---- bias + ReLU + pack H into hfr (registers) via shfl_xor(32) ----
    // Lane (ln,hi) owns H[m=ln][n = nt*32 + (r&3) + 8*(r>>2) + 4*hi].
    // B-frag (kc=nt, kh) needs n' = kc*32 + kh*16 + hi*8 + {0..7}:
    //   first 4 from group (2kh+hi) [own], last.. exchange: send group
    //   (2kh+1-hi), receive partner's -> verified by explicit lane tables.
    auto epiR = [&](const float* bias) {
        #pragma unroll
        for (int nt = 0; nt < 4; ++nt) {
            float rf[16];
            #pragma unroll
            for (int rq = 0; rq < 4; ++rq) {
                f32x4 bv = *(const f32x4*)(bias + nt * 32 + rq * 8 + hi * 4);
                #pragma unroll
                for (int j = 0; j < 4; ++j)
                    rf[rq * 4 + j] = fmaxf(acc[nt][rq * 4 + j] + bv[j], 0.f);
            }
            acc[nt] = fz;
            #pragma unroll
            for (int kh = 0; kh < 2; ++kh) {
                const int qo = (2 * kh + hi) * 4;        // own e-group
                const int qs = (2 * kh + (1 - hi)) * 4;  // group partner needs
                unsigned own0 = pk2(rf[qo],     rf[qo + 1]);
                unsigned own1 = pk2(rf[qo + 2], rf[qo + 3]);
                unsigned snd0 = pk2(rf[qs],     rf[qs + 1]);
                unsigned snd1 = pk2(rf[qs + 2], rf[qs + 3]);
                unsigned rcv0 = (unsigned)__shfl_xor((int)snd0, 32);
                unsigned rcv1 = (unsigned)__shfl_xor((int)snd1, 32);
                union { unsigned u[4]; bf16x8 v; } r;
                r.u[0] = hi ? rcv0 : own0;   // e0..1
                r.u[1] = hi ? rcv1 : own1;   // e2..3
                r.u[2] = hi ? own0 : rcv0;   // e4..5
                r.u[3] = hi ? own1 : rcv1;   // e6..7
                hfr[nt * 2 + kh] = r.v;
            }
        }
    };

#define PITER(C, VM)                                                          \
    {                                                                         \
        if constexpr ((C) + 3 < NCH) stageW((C) + 3);                         \
        __builtin_amdgcn_sched_barrier(0);                                    \
        if constexpr ((C) + 2 < NK1) {                                        \
            if constexpr (MODE == 0 && (C) + 2 >= 8)                          \
                loadBF(ic<(C) + 2>{}, fS[((C) + 2) % 3]);                     \
            else                                                              \
                loadBB(ic<(C) + 2>{}, bS[((C) + 2) % 3]);                     \
        }                                                                     \
        __builtin_amdgcn_sched_barrier(0);                                    \
        asm volatile("s_waitcnt vmcnt(" #VM ")" ::: "memory");                \
        __builtin_amdgcn_sched_barrier(0);                                    \
        __builtin_amdgcn_s_barrier();                                         \
        __builtin_amdgcn_sched_barrier(0);                                    \
        compute(ic<(C)>{});                                                   \
    }

    // prologue: S0,B0,S1,B1,S2 (order pinned)
    stageW(0);
    __builtin_amdgcn_sched_barrier(0);
    loadBB(ic<0>{}, bS[0]);
    __builtin_amdgcn_sched_barrier(0);
    stageW(1);
    __builtin_amdgcn_sched_barrier(0);
    loadBB(ic<1>{}, bS[1]);
    __builtin_amdgcn_sched_barrier(0);
    stageW(2);
    __builtin_amdgcn_sched_barrier(0);

    // vmcnt tables: r11-passed values verbatim.
    if constexpr (MODE == 0) {
        PITER(0, 12)  PITER(1, 12)  PITER(2, 12)  PITER(3, 14)
        PITER(4, 14)  PITER(5, 14)  PITER(6, 14)  PITER(7, 14)
        PITER(8, 14)  PITER(9, 14)  PITER(10, 12) PITER(11, 10)
        epiR(b1);
        PITER(12, 8)  PITER(13, 6)  PITER(14, 6)  PITER(15, 6)
        epiR(b2);
        PITER(16, 6)  PITER(17, 4)  PITER(18, 2)  PITER(19, 0)
    } else {
        PITER(0, 12)  PITER(1, 12)  PITER(2, 12)  PITER(3, 14)
        PITER(4, 14)  PITER(5, 14)  PITER(6, 12)  PITER(7, 10)
        epiR(b1);
        PITER(8, 8)   PITER(9, 6)   PITER(10, 6)  PITER(11, 6)
        epiR(b2);
        PITER(12, 6)  PITER(13, 4)  PITER(14, 2)  PITER(15, 0)
    }
#undef PITER

    // ================= bias3 + LayerNorm + residual (+ ybuf) =================
    float vsum = 0.f, vsq = 0.f;
    #pragma unroll
    for (int nt = 0; nt < 4; ++nt) {
        #pragma unroll
        for (int rq = 0; rq < 4; ++rq) {
            f32x4 bv = *(const f32x4*)(b3 + nt * 32 + rq * 8 + hi * 4);
            #pragma unroll
            for (int j = 0; j < 4; ++j) {
                float v = acc[nt][rq * 4 + j] + bv[j];
                acc[nt][rq * 4 + j] = v;
                vsum += v; vsq += v * v;
            }
        }
    }
    vsum += __shfl_xor(vsum, 32);
    vsq  += __shfl_xor(vsq, 32);
    const float mu = vsum * (1.f / DD);
    const float rs = rsqrtf(vsq * (1.f / DD) - mu * mu + LN_EPS);

    if (gm < NROWS) {
        const float* resid = ((MODE == 0) ? edgef : nodef) + (size_t)gm * DD;
        #pragma unroll
        for (int nt = 0; nt < 4; ++nt) {
            #pragma unroll
            for (int rq = 0; rq < 4; ++rq) {
                const int n0 = nt * 32 + rq * 8 + hi * 4;
                f32x4 gv = *(const f32x4*)(gamma + n0);
                f32x4 bv = *(const f32x4*)(beta + n0);
                f32x4 rv = *(const f32x4*)(resid + n0);
                float y[4];
                f32x4 o;
                #pragma unroll
                for (int j = 0; j < 4; ++j) {
                    y[j] = (acc[nt][rq * 4 + j] - mu) * rs * gv[j] + bv[j];
                    o[j] = y[j] + rv[j];
                }
                *(f32x4*)(outp + (size_t)gm * DD + n0) = o;
                if (MODE == 0) {
                    unsigned long long pkd =
                        (unsigned long long)pk2(y[0], y[1])
                      | ((unsigned long long)pk2(y[2], y[3]) << 32);
                    *(unsigned long long*)((char*)ybuf + (size_t)prow * 256 + n0 * 2) = pkd;
                }
            }
        }
    }
}

extern "C" void kernel_launch(void* const* d_in, const int* in_sizes, int n_in,
                              void* d_out, int out_size, void* d_ws, size_t ws_size,
                              hipStream_t stream) {
    const float* nodef = (const float*)d_in[0];
    const float* edgef = (const float*)d_in[1];
    const int* senders   = (const int*)d_in[2];
    const int* receivers = (const int*)d_in[3];
    const float* We1 = (const float*)d_in[4],  *be1 = (const float*)d_in[5];
    const float* We2 = (const float*)d_in[6],  *be2 = (const float*)d_in[7];
    const float* We3 = (const float*)d_in[8],  *be3 = (const float*)d_in[9];
    const float* ge  = (const float*)d_in[10], *bege = (const float*)d_in[11];
    const float* Wn1 = (const float*)d_in[12], *bn1 = (const float*)d_in[13];
    const float* Wn2 = (const float*)d_in[14], *bn2 = (const float*)d_in[15];
    const float* Wn3 = (const float*)d_in[16], *bn3 = (const float*)d_in[17];
    const float* gn  = (const float*)d_in[18], *begn = (const float*)d_in[19];

    float* out_node = (float*)d_out;
    float* out_edge = (float*)d_out + (size_t)NNODES * DD;

    char* ws = (char*)d_ws;
    size_t o = 0;
    unsigned short* aggb = (unsigned short*)(ws + o); o += (size_t)NNODES * 256;
    unsigned* ybuf = (unsigned*)(ws + o);             o += (size_t)NEDGES * 256;
    unsigned short* nodb = (unsigned short*)(ws + o); o += (size_t)NNODES * 256;
    char* img_e = ws + o;           o += 20 * 8192;
    char* img_n = ws + o;           o += 16 * 8192;
    int* cnt    = (int*)(ws + o);   o += NNODES * 4;
    int* cursor = (int*)(ws + o);   o += NNODES * 4;
    int* off    = (int*)(ws + o);   o += (NNODES + 4) * 4;
    int* part   = (int*)(ws + o);   o += NTH * 4;
    int* perm   = (int*)(ws + o);   o += NEDGES * 4;

    hipMemsetAsync(cnt, 0, NNODES * 4, stream);
    prepass<<<72 + 1024, NTH, 0, stream>>>(We1, We2, We3, Wn1, Wn2, Wn3,
                                           img_e, img_n,
                                           nodef, receivers, (uint4*)nodb, cnt);
    csr_scan1<<<NTH, NTH, 0, stream>>>(cnt, part);
    csr_scan2<<<1, NTH, 0, stream>>>(cnt, part, off, cursor);
    csr_fill<<<(NEDGES + NTH - 1) / NTH, NTH, 0, stream>>>(receivers, cursor, perm);

    mgn_mfma<0><<<dim3((NEDGES + 127) / 128), dim3(NTH), 0, stream>>>(
        nodef, edgef, nodb, senders, receivers, perm, img_e,
        be1, be2, be3, ge, bege, aggb, ybuf, out_edge);

    aggregate<<<(NNODES + 3) / 4, NTH, 0, stream>>>(ybuf, off, (unsigned*)aggb);

    mgn_mfma<1><<<dim3((NNODES + 127) / 128), dim3(NTH), 0, stream>>>(
        nodef, edgef, nodb, senders, receivers, perm, img_n,
        bn1, bn2, bn3, gn, begn, aggb, ybuf, out_node);
}

// Round 14
// 366.404 us; speedup vs baseline: 1.0788x; 1.0788x over previous
//
#include <hip/hip_runtime.h>

#define NNODES 50000
#define NEDGES 200000
#define DD 128
#define LN_EPS 1e-5f
#define NTH 256

typedef __attribute__((ext_vector_type(8))) short bf16x8;
typedef __attribute__((ext_vector_type(4))) float f32x4;
typedef __attribute__((ext_vector_type(16))) float f32x16;

template<int N> struct ic { static constexpr int value = N; };

__device__ __forceinline__ unsigned short bfr(float f) {
    union { float f; unsigned u; } v; v.f = f;
    return (unsigned short)((v.u + 0x7fffu + ((v.u >> 16) & 1u)) >> 16);
}
__device__ __forceinline__ unsigned pk2(float a, float b) {
    return (unsigned)bfr(a) | ((unsigned)bfr(b) << 16);
}
__device__ __forceinline__ void gload_lds16(const void* g, void* l) {
    __builtin_amdgcn_global_load_lds(
        (const __attribute__((address_space(1))) void*)g,
        (__attribute__((address_space(3))) void*)l, 16, 0, 0);
}

// ---------------------------------------------------------------------------
// Fused pre-pass: blocks [0,72)  -> weight image builder (r6-proven layout)
//                 blocks [72, +1024) -> nodef bf16 mirror + receiver histogram
// Weight image per k32 chunk c (8 KB): granule(nt, n32, ks):
//   byte = c*8192 + nt*2048 + n32*64 + ((ks ^ ((n32 + (n32>>2)) & 3)) << 4)
//   content: Wt[n = nt*32+n32][k = c*32 + ks*8 + e], e=0..7 (bf16)
// ---------------------------------------------------------------------------
__global__ __launch_bounds__(NTH)
void prepass(const float* __restrict__ We1, const float* __restrict__ We2,
             const float* __restrict__ We3, const float* __restrict__ Wn1,
             const float* __restrict__ Wn2, const float* __restrict__ Wn3,
             char* __restrict__ img_e, char* __restrict__ img_n,
             const float* __restrict__ nodef, const int* __restrict__ recv,
             uint4* __restrict__ nodb, int* __restrict__ cnt) {
    if (blockIdx.x < 72) {
        int tid = blockIdx.x * NTH + threadIdx.x;
        const float* W; char* dst; int q;
        if      (tid <  6144) { W = We1; dst = img_e;             q = tid;         }
        else if (tid <  8192) { W = We2; dst = img_e + 12 * 8192; q = tid - 6144;  }
        else if (tid < 10240) { W = We3; dst = img_e + 16 * 8192; q = tid - 8192;  }
        else if (tid < 14336) { W = Wn1; dst = img_n;             q = tid - 10240; }
        else if (tid < 16384) { W = Wn2; dst = img_n + 8 * 8192;  q = tid - 14336; }
        else if (tid < 18432) { W = Wn3; dst = img_n + 12 * 8192; q = tid - 16384; }
        else return;
        int c = q >> 9, rem = q & 511;
        int nt = rem >> 7, r2 = rem & 127, n32 = r2 >> 2, ks = r2 & 3;
        int n = nt * 32 + n32;
        int sx = (n32 + (n32 >> 2)) & 3;
        int k0 = c * 32 + ks * 8;
        unsigned short o[8];
        #pragma unroll
        for (int e = 0; e < 8; ++e)
            o[e] = bfr(W[(size_t)(k0 + e) * DD + n]);
        uint4 val;
        val.x = (unsigned)o[0] | ((unsigned)o[1] << 16);
        val.y = (unsigned)o[2] | ((unsigned)o[3] << 16);
        val.z = (unsigned)o[4] | ((unsigned)o[5] << 16);
        val.w = (unsigned)o[6] | ((unsigned)o[7] << 16);
        *(uint4*)(dst + (size_t)c * 8192 + nt * 2048 + n32 * 64 + ((ks ^ sx) << 4)) = val;
    } else {
        const int b = blockIdx.x - 72;
        const int tid0 = b * NTH + threadIdx.x;
        if (tid0 < NEDGES) atomicAdd(&cnt[recv[tid0]], 1);
        const int NG = NNODES * 16;
        for (int g = tid0; g < NG; g += 1024 * NTH) {
            f32x4 a = ((const f32x4*)nodef)[g * 2];
            f32x4 bb = ((const f32x4*)nodef)[g * 2 + 1];
            uint4 o;
            o.x = pk2(a[0], a[1]); o.y = pk2(a[2], a[3]);
            o.z = pk2(bb[0], bb[1]); o.w = pk2(bb[2], bb[3]);
            nodb[g] = o;
        }
    }
}

// ---------------------------------------------------------------------------
// CSR: 2-level scan + fill (stores perm[e] = CSR position of edge e)
// ---------------------------------------------------------------------------
__global__ __launch_bounds__(NTH)
void csr_scan1(const int* __restrict__ cnt, int* __restrict__ part) {
    __shared__ int red[NTH];
    const int b = blockIdx.x, t = threadIdx.x;
    const int base = b * 196;
    int s = 0;
    for (int i = t; i < 196; i += NTH) {
        int idx = base + i;
        if (idx < NNODES) s += cnt[idx];
    }
    red[t] = s;
    __syncthreads();
    for (int d = NTH / 2; d > 0; d >>= 1) {
        if (t < d) red[t] += red[t + d];
        __syncthreads();
    }
    if (t == 0) part[b] = red[0];
}

__global__ __launch_bounds__(NTH)
void csr_scan2(const int* __restrict__ cnt, const int* __restrict__ part,
               int* __restrict__ off, int* __restrict__ cursor) {
    __shared__ int sp[NTH];
    const int t = threadIdx.x;
    sp[t] = part[t];
    __syncthreads();
    for (int d = 1; d < NTH; d <<= 1) {
        int v = (t >= d) ? sp[t - d] : 0;
        __syncthreads();
        sp[t] += v;
        __syncthreads();
    }
    int run = (t == 0) ? 0 : sp[t - 1];
    const int base = t * 196;
    for (int i = 0; i < 196; ++i) {
        int idx = base + i;
        if (idx < NNODES) { off[idx] = run; cursor[idx] = run; run += cnt[idx]; }
    }
    if (t == NTH - 1) off[NNODES] = NEDGES;
}

__global__ void csr_fill(const int* __restrict__ recv, int* __restrict__ cursor,
                         int* __restrict__ perm) {
    int e = blockIdx.x * NTH + threadIdx.x;
    if (e < NEDGES) {
        int p = atomicAdd(&cursor[recv[e]], 1);
        perm[e] = p;
    }
}

// ---------------------------------------------------------------------------
// Aggregate (bf16): ybuf is CSR-ordered -> pure streaming reads.
// ---------------------------------------------------------------------------
__global__ __launch_bounds__(NTH)
void aggregate(const unsigned* __restrict__ ybuf,
               const int* __restrict__ off,
               unsigned* __restrict__ aggb) {
    const int n = blockIdx.x * 4 + (threadIdx.x >> 6);
    const int l = threadIdx.x & 63;
    if (n >= NNODES) return;
    const int j0 = off[n], j1 = off[n + 1];
    float sx = 0.f, sy = 0.f;
    int j = j0;
    for (; j + 4 <= j1; j += 4) {
        unsigned v0 = ybuf[(size_t)j * 64 + l];
        unsigned v1 = ybuf[(size_t)(j + 1) * 64 + l];
        unsigned v2 = ybuf[(size_t)(j + 2) * 64 + l];
        unsigned v3 = ybuf[(size_t)(j + 3) * 64 + l];
        sx += __uint_as_float(v0 << 16) + __uint_as_float(v1 << 16)
            + __uint_as_float(v2 << 16) + __uint_as_float(v3 << 16);
        sy += __uint_as_float(v0 & 0xffff0000u) + __uint_as_float(v1 & 0xffff0000u)
            + __uint_as_float(v2 & 0xffff0000u) + __uint_as_float(v3 & 0xffff0000u);
    }
    for (; j < j1; ++j) {
        unsigned v = ybuf[(size_t)j * 64 + l];
        sx += __uint_as_float(v << 16);
        sy += __uint_as_float(v & 0xffff0000u);
    }
    aggb[(size_t)n * 64 + l] = pk2(sx, sy);
}

// ---------------------------------------------------------------------------
// Fused MLP, 32x32x16 MFMA (r13 structure, passed; launch_bounds relaxed so
// the allocator is NOT capped at 64 VGPR -> no scratch spills).
// H1/H2 in registers (hfr[8], shfl_xor(32) exchange, r13-verified).
// LDS = 40 KB (5x8KB Wbuf) -> 4 blocks/CU if VGPR <= 128.
// ---------------------------------------------------------------------------
template<int MODE>
__global__ __launch_bounds__(NTH, 2)
void mgn_mfma(const float* __restrict__ nodef, const float* __restrict__ edgef,
              const unsigned short* __restrict__ nodb,
              const int* __restrict__ senders, const int* __restrict__ receivers,
              const int* __restrict__ perm,
              const char* __restrict__ img,
              const float* __restrict__ b1, const float* __restrict__ b2,
              const float* __restrict__ b3,
              const float* __restrict__ gamma, const float* __restrict__ beta,
              const unsigned short* __restrict__ aggb, unsigned* __restrict__ ybuf,
              float* __restrict__ outp)
{
    __shared__ char Wbuf[5 * 8192];   // 5 rotating k32 weight chunks (40 KB)

    const int t  = threadIdx.x;
    const int w  = t >> 6;
    const int l  = t & 63;
    const int ln = l & 31;
    const int hi = l >> 5;
    const int row0 = blockIdx.x * 128;
    const int gm = row0 + w * 32 + ln;
    constexpr int NROWS = (MODE == 0) ? NEDGES : NNODES;
    constexpr int NK1   = (MODE == 0) ? 12 : 8;
    constexpr int NCH   = NK1 + 8;
    const int gmc = gm < NROWS ? gm : NROWS - 1;
    const int sxA = (ln + (ln >> 2)) & 3;

    int srow = 0, rrow = 0, prow = 0;
    if (MODE == 0) { srow = senders[gmc]; rrow = receivers[gmc]; prow = perm[gmc]; }

    const f32x16 fz = {0.f,0.f,0.f,0.f,0.f,0.f,0.f,0.f,
                       0.f,0.f,0.f,0.f,0.f,0.f,0.f,0.f};
    f32x16 acc[4];
    #pragma unroll
    for (int nt = 0; nt < 4; ++nt) acc[nt] = fz;

    bf16x8 bS[3][2];   // bf16 B rotation, lead 2
    f32x4  fS[3][4];   // fp32 B rotation (edge chunks 8..11), lead 2
    bf16x8 hfr[8];     // H fragments in registers: [kc*2 + kh]

    auto stageW = [&](int c) {
        const char* src = img + (size_t)c * 8192 + t * 16;
        char* dstl = Wbuf + (c % 5) * 8192 + t * 16;
        gload_lds16(src, dstl);
        gload_lds16(src + 4096, dstl + 4096);
    };

    auto loadBB = [&](auto CC, bf16x8* dst) {
        constexpr int c = decltype(CC)::value;
        const unsigned short* base;
        if constexpr (MODE == 0) {
            base = (c < 4) ? nodb + (size_t)srow * DD : nodb + (size_t)rrow * DD;
        } else {
            base = (c < 4) ? nodb + (size_t)gmc * DD : aggb + (size_t)gmc * DD;
        }
        const char* p = (const char*)base + (c & 3) * 64 + hi * 16;
        dst[0] = *(const bf16x8*)p;
        dst[1] = *(const bf16x8*)(p + 32);
    };

    auto loadBF = [&](auto CC, f32x4* dst) {
        constexpr int c = decltype(CC)::value;
        const float* p = edgef + (size_t)gmc * DD + (c & 3) * 32 + hi * 8;
        dst[0] = *(const f32x4*)p;
        dst[1] = *(const f32x4*)(p + 4);
        dst[2] = *(const f32x4*)(p + 16);
        dst[3] = *(const f32x4*)(p + 20);
    };

    auto cvtB = [&](const f32x4* br) {
        union { unsigned u[4]; bf16x8 v; } r;
        r.u[0] = pk2(br[0][0], br[0][1]);
        r.u[1] = pk2(br[0][2], br[0][3]);
        r.u[2] = pk2(br[1][0], br[1][1]);
        r.u[3] = pk2(br[1][2], br[1][3]);
        return r.v;
    };

    auto getB = [&](auto CC, int kh) -> bf16x8 {
        constexpr int c = decltype(CC)::value;
        if constexpr (c >= NK1) {
            return hfr[((c - NK1) & 3) * 2 + kh];
        } else if constexpr (MODE == 0 && c >= 8) {
            return cvtB(&fS[c % 3][kh * 2]);
        } else {
            return bS[c % 3][kh];
        }
    };

    auto compute = [&](auto CC) {
        constexpr int c = decltype(CC)::value;
        const char* bp = Wbuf + (c % 5) * 8192 + ln * 64;
        #pragma unroll
        for (int kh = 0; kh < 2; ++kh) {
            bf16x8 b = getB(CC, kh);
            #pragma unroll
            for (int nt = 0; nt < 4; ++nt) {
                bf16x8 a = *(const bf16x8*)(bp + nt * 2048
                            + (((kh * 2 + hi) ^ sxA) << 4));
                acc[nt] = __builtin_amdgcn_mfma_f32_32x32x16_bf16(a, b, acc[nt], 0, 0, 0);
            }
        }
    };

    // ---- bias + ReLU + pack H into hfr (registers) via shfl_xor(32) ----
    // (r13-verified on hardware: absmax matched LDS-Hb version exactly)
    auto epiR = [&](const float* bias) {
        #pragma unroll
        for (int nt = 0; nt < 4; ++nt) {
            float rf[16];
            #pragma unroll
            for (int rq = 0; rq < 4; ++rq) {
                f32x4 bv = *(const f32x4*)(bias + nt * 32 + rq * 8 + hi * 4);
                #pragma unroll
                for (int j = 0; j < 4; ++j)
                    rf[rq * 4 + j] = fmaxf(acc[nt][rq * 4 + j] + bv[j], 0.f);
            }
            acc[nt] = fz;
            #pragma unroll
            for (int kh = 0; kh < 2; ++kh) {
                const int qo = (2 * kh + hi) * 4;        // own e-group
                const int qs = (2 * kh + (1 - hi)) * 4;  // group partner needs
                unsigned own0 = pk2(rf[qo],     rf[qo + 1]);
                unsigned own1 = pk2(rf[qo + 2], rf[qo + 3]);
                unsigned snd0 = pk2(rf[qs],     rf[qs + 1]);
                unsigned snd1 = pk2(rf[qs + 2], rf[qs + 3]);
                unsigned rcv0 = (unsigned)__shfl_xor((int)snd0, 32);
                unsigned rcv1 = (unsigned)__shfl_xor((int)snd1, 32);
                union { unsigned u[4]; bf16x8 v; } r;
                r.u[0] = hi ? rcv0 : own0;   // e0..1
                r.u[1] = hi ? rcv1 : own1;   // e2..3
                r.u[2] = hi ? own0 : rcv0;   // e4..5
                r.u[3] = hi ? own1 : rcv1;   // e6..7
                hfr[nt * 2 + kh] = r.v;
            }
        }
    };

#define PITER(C, VM)                                                          \
    {                                                                         \
        if constexpr ((C) + 3 < NCH) stageW((C) + 3);                         \
        __builtin_amdgcn_sched_barrier(0);                                    \
        if constexpr ((C) + 2 < NK1) {                                        \
            if constexpr (MODE == 0 && (C) + 2 >= 8)                          \
                loadBF(ic<(C) + 2>{}, fS[((C) + 2) % 3]);                     \
            else                                                              \
                loadBB(ic<(C) + 2>{}, bS[((C) + 2) % 3]);                     \
        }                                                                     \
        __builtin_amdgcn_sched_barrier(0);                                    \
        asm volatile("s_waitcnt vmcnt(" #VM ")" ::: "memory");                \
        __builtin_amdgcn_sched_barrier(0);                                    \
        __builtin_amdgcn_s_barrier();                                         \
        __builtin_amdgcn_sched_barrier(0);                                    \
        compute(ic<(C)>{});                                                   \
    }

    // prologue: S0,B0,S1,B1,S2 (order pinned)
    stageW(0);
    __builtin_amdgcn_sched_barrier(0);
    loadBB(ic<0>{}, bS[0]);
    __builtin_amdgcn_sched_barrier(0);
    stageW(1);
    __builtin_amdgcn_sched_barrier(0);
    loadBB(ic<1>{}, bS[1]);
    __builtin_amdgcn_sched_barrier(0);
    stageW(2);
    __builtin_amdgcn_sched_barrier(0);

    // vmcnt tables: r11-passed values verbatim.
    if constexpr (MODE == 0) {
        PITER(0, 12)  PITER(1, 12)  PITER(2, 12)  PITER(3, 14)
        PITER(4, 14)  PITER(5, 14)  PITER(6, 14)  PITER(7, 14)
        PITER(8, 14)  PITER(9, 14)  PITER(10, 12) PITER(11, 10)
        epiR(b1);
        PITER(12, 8)  PITER(13, 6)  PITER(14, 6)  PITER(15, 6)
        epiR(b2);
        PITER(16, 6)  PITER(17, 4)  PITER(18, 2)  PITER(19, 0)
    } else {
        PITER(0, 12)  PITER(1, 12)  PITER(2, 12)  PITER(3, 14)
        PITER(4, 14)  PITER(5, 14)  PITER(6, 12)  PITER(7, 10)
        epiR(b1);
        PITER(8, 8)   PITER(9, 6)   PITER(10, 6)  PITER(11, 6)
        epiR(b2);
        PITER(12, 6)  PITER(13, 4)  PITER(14, 2)  PITER(15, 0)
    }
#undef PITER

    // ================= bias3 + LayerNorm + residual (+ ybuf) =================
    float vsum = 0.f, vsq = 0.f;
    #pragma unroll
    for (int nt = 0; nt < 4; ++nt) {
        #pragma unroll
        for (int rq = 0; rq < 4; ++rq) {
            f32x4 bv = *(const f32x4*)(b3 + nt * 32 + rq * 8 + hi * 4);
            #pragma unroll
            for (int j = 0; j < 4; ++j) {
                float v = acc[nt][rq * 4 + j] + bv[j];
                acc[nt][rq * 4 + j] = v;
                vsum += v; vsq += v * v;
            }
        }
    }
    vsum += __shfl_xor(vsum, 32);
    vsq  += __shfl_xor(vsq, 32);
    const float mu = vsum * (1.f / DD);
    const float rs = rsqrtf(vsq * (1.f / DD) - mu * mu + LN_EPS);

    if (gm < NROWS) {
        const float* resid = ((MODE == 0) ? edgef : nodef) + (size_t)gm * DD;
        #pragma unroll
        for (int nt = 0; nt < 4; ++nt) {
            #pragma unroll
            for (int rq = 0; rq < 4; ++rq) {
                const int n0 = nt * 32 + rq * 8 + hi * 4;
                f32x4 gv = *(const f32x4*)(gamma + n0);
                f32x4 bv = *(const f32x4*)(beta + n0);
                f32x4 rv = *(const f32x4*)(resid + n0);
                float y[4];
                f32x4 o;
                #pragma unroll
                for (int j = 0; j < 4; ++j) {
                    y[j] = (acc[nt][rq * 4 + j] - mu) * rs * gv[j] + bv[j];
                    o[j] = y[j] + rv[j];
                }
                *(f32x4*)(outp + (size_t)gm * DD + n0) = o;
                if (MODE == 0) {
                    unsigned long long pkd =
                        (unsigned long long)pk2(y[0], y[1])
                      | ((unsigned long long)pk2(y[2], y[3]) << 32);
                    *(unsigned long long*)((char*)ybuf + (size_t)prow * 256 + n0 * 2) = pkd;
                }
            }
        }
    }
}

extern "C" void kernel_launch(void* const* d_in, const int* in_sizes, int n_in,
                              void* d_out, int out_size, void* d_ws, size_t ws_size,
                              hipStream_t stream) {
    const float* nodef = (const float*)d_in[0];
    const float* edgef = (const float*)d_in[1];
    const int* senders   = (const int*)d_in[2];
    const int* receivers = (const int*)d_in[3];
    const float* We1 = (const float*)d_in[4],  *be1 = (const float*)d_in[5];
    const float* We2 = (const float*)d_in[6],  *be2 = (const float*)d_in[7];
    const float* We3 = (const float*)d_in[8],  *be3 = (const float*)d_in[9];
    const float* ge  = (const float*)d_in[10], *bege = (const float*)d_in[11];
    const float* Wn1 = (const float*)d_in[12], *bn1 = (const float*)d_in[13];
    const float* Wn2 = (const float*)d_in[14], *bn2 = (const float*)d_in[15];
    const float* Wn3 = (const float*)d_in[16], *bn3 = (const float*)d_in[17];
    const float* gn  = (const float*)d_in[18], *begn = (const float*)d_in[19];

    float* out_node = (float*)d_out;
    float* out_edge = (float*)d_out + (size_t)NNODES * DD;

    char* ws = (char*)d_ws;
    size_t o = 0;
    unsigned short* aggb = (unsigned short*)(ws + o); o += (size_t)NNODES * 256;
    unsigned* ybuf = (unsigned*)(ws + o);             o += (size_t)NEDGES * 256;
    unsigned short* nodb = (unsigned short*)(ws + o); o += (size_t)NNODES * 256;
    char* img_e = ws + o;           o += 20 * 8192;
    char* img_n = ws + o;           o += 16 * 8192;
    int* cnt    = (int*)(ws + o);   o += NNODES * 4;
    int* cursor = (int*)(ws + o);   o += NNODES * 4;
    int* off    = (int*)(ws + o);   o += (NNODES + 4) * 4;
    int* part   = (int*)(ws + o);   o += NTH * 4;
    int* perm   = (int*)(ws + o);   o += NEDGES * 4;

    hipMemsetAsync(cnt, 0, NNODES * 4, stream);
    prepass<<<72 + 1024, NTH, 0, stream>>>(We1, We2, We3, Wn1, Wn2, Wn3,
                                           img_e, img_n,
                                           nodef, receivers, (uint4*)nodb, cnt);
    csr_scan1<<<NTH, NTH, 0, stream>>>(cnt, part);
    csr_scan2<<<1, NTH, 0, stream>>>(cnt, part, off, cursor);
    csr_fill<<<(NEDGES + NTH - 1) / NTH, NTH, 0, stream>>>(receivers, cursor, perm);

    mgn_mfma<0><<<dim3((NEDGES + 127) / 128), dim3(NTH), 0, stream>>>(
        nodef, edgef, nodb, senders, receivers, perm, img_e,
        be1, be2, be3, ge, bege, aggb, ybuf, out_edge);

    aggregate<<<(NNODES + 3) / 4, NTH, 0, stream>>>(ybuf, off, (unsigned*)aggb);

    mgn_mfma<1><<<dim3((NNODES + 127) / 128), dim3(NTH), 0, stream>>>(
        nodef, edgef, nodb, senders, receivers, perm, img_n,
        bn1, bn2, bn3, gn, begn, aggb, ybuf, out_node);
}

// Round 15
// 325.549 us; speedup vs baseline: 1.2142x; 1.1255x over previous
//
#include <hip/hip_runtime.h>

#define NNODES 50000
#define NEDGES 200000
#define DD 128
#define LN_EPS 1e-5f
#define NTH 256

typedef __attribute__((ext_vector_type(8))) short bf16x8;
typedef __attribute__((ext_vector_type(4))) float f32x4;
typedef __attribute__((ext_vector_type(16))) float f32x16;

template<int N> struct ic { static constexpr int value = N; };

__device__ __forceinline__ unsigned short bfr(float f) {
    union { float f; unsigned u; } v; v.f = f;
    return (unsigned short)((v.u + 0x7fffu + ((v.u >> 16) & 1u)) >> 16);
}
__device__ __forceinline__ unsigned pk2(float a, float b) {
    return (unsigned)bfr(a) | ((unsigned)bfr(b) << 16);
}
__device__ __forceinline__ void gload_lds16(const void* g, void* l) {
    __builtin_amdgcn_global_load_lds(
        (const __attribute__((address_space(1))) void*)g,
        (__attribute__((address_space(3))) void*)l, 16, 0, 0);
}

// ---------------------------------------------------------------------------
// Fused pre-pass: blocks [0,72)  -> weight image builder (r6-proven layout)
//                 blocks [72, +1024) -> nodef bf16 mirror + receiver histogram
// Weight image per k32 chunk c (8 KB): granule(nt, n32, ks):
//   byte = c*8192 + nt*2048 + n32*64 + ((ks ^ ((n32 + (n32>>2)) & 3)) << 4)
//   content: Wt[n = nt*32+n32][k = c*32 + ks*8 + e], e=0..7 (bf16)
// ---------------------------------------------------------------------------
__global__ __launch_bounds__(NTH)
void prepass(const float* __restrict__ We1, const float* __restrict__ We2,
             const float* __restrict__ We3, const float* __restrict__ Wn1,
             const float* __restrict__ Wn2, const float* __restrict__ Wn3,
             char* __restrict__ img_e, char* __restrict__ img_n,
             const float* __restrict__ nodef, const int* __restrict__ recv,
             uint4* __restrict__ nodb, int* __restrict__ cnt) {
    if (blockIdx.x < 72) {
        int tid = blockIdx.x * NTH + threadIdx.x;
        const float* W; char* dst; int q;
        if      (tid <  6144) { W = We1; dst = img_e;             q = tid;         }
        else if (tid <  8192) { W = We2; dst = img_e + 12 * 8192; q = tid - 6144;  }
        else if (tid < 10240) { W = We3; dst = img_e + 16 * 8192; q = tid - 8192;  }
        else if (tid < 14336) { W = Wn1; dst = img_n;             q = tid - 10240; }
        else if (tid < 16384) { W = Wn2; dst = img_n + 8 * 8192;  q = tid - 14336; }
        else if (tid < 18432) { W = Wn3; dst = img_n + 12 * 8192; q = tid - 16384; }
        else return;
        int c = q >> 9, rem = q & 511;
        int nt = rem >> 7, r2 = rem & 127, n32 = r2 >> 2, ks = r2 & 3;
        int n = nt * 32 + n32;
        int sx = (n32 + (n32 >> 2)) & 3;
        int k0 = c * 32 + ks * 8;
        unsigned short o[8];
        #pragma unroll
        for (int e = 0; e < 8; ++e)
            o[e] = bfr(W[(size_t)(k0 + e) * DD + n]);
        uint4 val;
        val.x = (unsigned)o[0] | ((unsigned)o[1] << 16);
        val.y = (unsigned)o[2] | ((unsigned)o[3] << 16);
        val.z = (unsigned)o[4] | ((unsigned)o[5] << 16);
        val.w = (unsigned)o[6] | ((unsigned)o[7] << 16);
        *(uint4*)(dst + (size_t)c * 8192 + nt * 2048 + n32 * 64 + ((ks ^ sx) << 4)) = val;
    } else {
        const int b = blockIdx.x - 72;
        const int tid0 = b * NTH + threadIdx.x;
        if (tid0 < NEDGES) atomicAdd(&cnt[recv[tid0]], 1);
        const int NG = NNODES * 16;
        for (int g = tid0; g < NG; g += 1024 * NTH) {
            f32x4 a = ((const f32x4*)nodef)[g * 2];
            f32x4 bb = ((const f32x4*)nodef)[g * 2 + 1];
            uint4 o;
            o.x = pk2(a[0], a[1]); o.y = pk2(a[2], a[3]);
            o.z = pk2(bb[0], bb[1]); o.w = pk2(bb[2], bb[3]);
            nodb[g] = o;
        }
    }
}

// ---------------------------------------------------------------------------
// CSR: single-block scan (r2-proven) + fill (stores perm[e])
// ---------------------------------------------------------------------------
__global__ __launch_bounds__(1024)
void csr_scan(const int* __restrict__ cnt, int* __restrict__ off, int* __restrict__ cursor) {
    __shared__ int part[1024];
    const int t = threadIdx.x;
    const int CH = (NNODES + 1023) / 1024;
    const int base = t * CH;
    int s = 0;
    for (int i = 0; i < CH; ++i) {
        int idx = base + i;
        if (idx < NNODES) s += cnt[idx];
    }
    part[t] = s;
    __syncthreads();
    for (int d = 1; d < 1024; d <<= 1) {
        int v = (t >= d) ? part[t - d] : 0;
        __syncthreads();
        part[t] += v;
        __syncthreads();
    }
    int run = (t == 0) ? 0 : part[t - 1];
    for (int i = 0; i < CH; ++i) {
        int idx = base + i;
        if (idx < NNODES) {
            off[idx] = run; cursor[idx] = run;
            run += cnt[idx];
        }
    }
    if (t == 1023) off[NNODES] = NEDGES;
}

__global__ void csr_fill(const int* __restrict__ recv, int* __restrict__ cursor,
                         int* __restrict__ perm) {
    int e = blockIdx.x * NTH + threadIdx.x;
    if (e < NEDGES) {
        int p = atomicAdd(&cursor[recv[e]], 1);
        perm[e] = p;
    }
}

// ---------------------------------------------------------------------------
// Aggregate (bf16): ybuf is CSR-ordered -> pure streaming reads.
// ---------------------------------------------------------------------------
__global__ __launch_bounds__(NTH)
void aggregate(const unsigned* __restrict__ ybuf,
               const int* __restrict__ off,
               unsigned* __restrict__ aggb) {
    const int n = blockIdx.x * 4 + (threadIdx.x >> 6);
    const int l = threadIdx.x & 63;
    if (n >= NNODES) return;
    const int j0 = off[n], j1 = off[n + 1];
    float sx = 0.f, sy = 0.f;
    int j = j0;
    for (; j + 4 <= j1; j += 4) {
        unsigned v0 = ybuf[(size_t)j * 64 + l];
        unsigned v1 = ybuf[(size_t)(j + 1) * 64 + l];
        unsigned v2 = ybuf[(size_t)(j + 2) * 64 + l];
        unsigned v3 = ybuf[(size_t)(j + 3) * 64 + l];
        sx += __uint_as_float(v0 << 16) + __uint_as_float(v1 << 16)
            + __uint_as_float(v2 << 16) + __uint_as_float(v3 << 16);
        sy += __uint_as_float(v0 & 0xffff0000u) + __uint_as_float(v1 & 0xffff0000u)
            + __uint_as_float(v2 & 0xffff0000u) + __uint_as_float(v3 & 0xffff0000u);
    }
    for (; j < j1; ++j) {
        unsigned v = ybuf[(size_t)j * 64 + l];
        sx += __uint_as_float(v << 16);
        sy += __uint_as_float(v & 0xffff0000u);
    }
    aggb[(size_t)n * 64 + l] = pk2(sx, sy);
}

// ---------------------------------------------------------------------------
// Fused MLP, 32x32x16 MFMA (r12 structure verbatim = best validated config).
// Two-chunk (BK=64) macro-iterations, 6 Wbuf buffers, barrier-first ordering
// (safe: compute(M-1)'s ds_reads complete before its MFMA lgkmcnt waits,
// which precede barrier(M) in program order; sched_barrier(0) pins).
// ADDED: s_setprio(1) around the MFMA compute pair (T5).
// B: 4-slot register rings (bf16 nodb/aggb; fp32 edgef stream on edge 8..11).
// H1/H2: wave-private swizzled LDS (r6-proven epiH/loadBH).
// ---------------------------------------------------------------------------
template<int MODE>
__global__ __launch_bounds__(NTH, 2)
void mgn_mfma(const float* __restrict__ nodef, const float* __restrict__ edgef,
              const unsigned short* __restrict__ nodb,
              const int* __restrict__ senders, const int* __restrict__ receivers,
              const int* __restrict__ perm,
              const char* __restrict__ img,
              const float* __restrict__ b1, const float* __restrict__ b2,
              const float* __restrict__ b3,
              const float* __restrict__ gamma, const float* __restrict__ beta,
              const unsigned short* __restrict__ aggb, unsigned* __restrict__ ybuf,
              float* __restrict__ outp)
{
    __shared__ char Wbuf[6 * 8192];   // 6 rotating k32 weight chunks (3 pairs)
    __shared__ char Hb[4 * 8192];     // per-wave 32 rows x 128 k bf16, swizzled

    const int t  = threadIdx.x;
    const int w  = t >> 6;
    const int l  = t & 63;
    const int ln = l & 31;
    const int hi = l >> 5;
    const int row0 = blockIdx.x * 128;
    const int gm = row0 + w * 32 + ln;
    constexpr int NROWS = (MODE == 0) ? NEDGES : NNODES;
    constexpr int NK1   = (MODE == 0) ? 12 : 8;
    constexpr int NCH   = NK1 + 8;
    const int gmc = gm < NROWS ? gm : NROWS - 1;
    const int sxA = (ln + (ln >> 2)) & 3;
    const int sxH = ln & 15;

    int srow = 0, rrow = 0, prow = 0;
    if (MODE == 0) { srow = senders[gmc]; rrow = receivers[gmc]; prow = perm[gmc]; }

    const f32x16 fz = {0.f,0.f,0.f,0.f,0.f,0.f,0.f,0.f,
                       0.f,0.f,0.f,0.f,0.f,0.f,0.f,0.f};
    f32x16 acc[4];
    #pragma unroll
    for (int nt = 0; nt < 4; ++nt) acc[nt] = fz;

    bf16x8 bS[4][2];   // bf16 B ring (4 chunk slots)
    f32x4  fS[4][4];   // fp32 B ring (edge chunks 8..11)

    auto stageW = [&](int c) {
        const char* src = img + (size_t)c * 8192 + t * 16;
        char* dstl = Wbuf + (c % 6) * 8192 + t * 16;
        gload_lds16(src, dstl);
        gload_lds16(src + 4096, dstl + 4096);
    };

    auto loadBB = [&](auto CC, bf16x8* dst) {
        constexpr int c = decltype(CC)::value;
        const unsigned short* base;
        if constexpr (MODE == 0) {
            base = (c < 4) ? nodb + (size_t)srow * DD : nodb + (size_t)rrow * DD;
        } else {
            base = (c < 4) ? nodb + (size_t)gmc * DD : aggb + (size_t)gmc * DD;
        }
        const char* p = (const char*)base + (c & 3) * 64 + hi * 16;
        dst[0] = *(const bf16x8*)p;
        dst[1] = *(const bf16x8*)(p + 32);
    };

    auto loadBF = [&](auto CC, f32x4* dst) {
        constexpr int c = decltype(CC)::value;
        const float* p = edgef + (size_t)gmc * DD + (c & 3) * 32 + hi * 8;
        dst[0] = *(const f32x4*)p;
        dst[1] = *(const f32x4*)(p + 4);
        dst[2] = *(const f32x4*)(p + 16);
        dst[3] = *(const f32x4*)(p + 20);
    };

    auto cvtB = [&](const f32x4* br) {
        union { unsigned u[4]; bf16x8 v; } r;
        r.u[0] = pk2(br[0][0], br[0][1]);
        r.u[1] = pk2(br[0][2], br[0][3]);
        r.u[2] = pk2(br[1][0], br[1][1]);
        r.u[3] = pk2(br[1][2], br[1][3]);
        return r.v;
    };

    auto loadBH = [&](int ks, int kh) {
        const char* p = Hb + w * 8192 + ln * 256
                      + (((ks * 4 + kh * 2 + hi) ^ sxH) << 4);
        return *(const bf16x8*)p;
    };

    auto getB = [&](auto CC, int kh) -> bf16x8 {
        constexpr int c = decltype(CC)::value;
        if constexpr (c >= NK1) {
            return loadBH((c - NK1) & 3, kh);
        } else if constexpr (MODE == 0 && c >= 8) {
            return cvtB(&fS[c & 3][kh * 2]);
        } else {
            return bS[c & 3][kh];
        }
    };

    auto compute = [&](auto CC) {
        constexpr int c = decltype(CC)::value;
        const char* bp = Wbuf + (c % 6) * 8192 + ln * 64;
        #pragma unroll
        for (int kh = 0; kh < 2; ++kh) {
            bf16x8 b = getB(CC, kh);
            #pragma unroll
            for (int nt = 0; nt < 4; ++nt) {
                bf16x8 a = *(const bf16x8*)(bp + nt * 2048
                            + (((kh * 2 + hi) ^ sxA) << 4));
                acc[nt] = __builtin_amdgcn_mfma_f32_32x32x16_bf16(a, b, acc[nt], 0, 0, 0);
            }
        }
    };

    auto epiH = [&](const float* bias) {
        #pragma unroll
        for (int nt = 0; nt < 4; ++nt) {
            #pragma unroll
            for (int rq = 0; rq < 4; ++rq) {
                f32x4 bv = *(const f32x4*)(bias + nt * 32 + rq * 8 + hi * 4);
                unsigned short h[4];
                #pragma unroll
                for (int j = 0; j < 4; ++j)
                    h[j] = bfr(fmaxf(acc[nt][rq * 4 + j] + bv[j], 0.f));
                char* p = Hb + w * 8192 + ln * 256
                        + (((nt * 4 + rq) ^ sxH) << 4) + hi * 8;
                unsigned lo = (unsigned)h[0] | ((unsigned)h[1] << 16);
                unsigned hx = (unsigned)h[2] | ((unsigned)h[3] << 16);
                *(unsigned long long*)p =
                    (unsigned long long)lo | ((unsigned long long)hx << 32);
            }
            acc[nt] = fz;
        }
    };

    auto loadB = [&](auto CC) {
        constexpr int c = decltype(CC)::value;
        if constexpr (c < NK1) {
            if constexpr (MODE == 0 && c >= 8) loadBF(CC, fS[c & 3]);
            else                               loadBB(CC, bS[c & 3]);
        }
    };

// Macro-iter M: chunks (2M, 2M+1). barrier -> stage pair (2M+4,2M+5) ->
// B pair (2M+2,2M+3) -> counted vmcnt -> setprio(1) compute pair setprio(0).
#define PITER2(M, VM)                                                         \
    {                                                                         \
        __builtin_amdgcn_s_barrier();                                         \
        __builtin_amdgcn_sched_barrier(0);                                    \
        if constexpr (2*(M) + 4 < NCH) stageW(2*(M) + 4);                     \
        if constexpr (2*(M) + 5 < NCH) stageW(2*(M) + 5);                     \
        __builtin_amdgcn_sched_barrier(0);                                    \
        loadB(ic<2*(M) + 2>{});                                               \
        loadB(ic<2*(M) + 3>{});                                               \
        __builtin_amdgcn_sched_barrier(0);                                    \
        asm volatile("s_waitcnt vmcnt(" #VM ")" ::: "memory");                \
        __builtin_amdgcn_sched_barrier(0);                                    \
        __builtin_amdgcn_s_setprio(1);                                        \
        compute(ic<2*(M)>{});                                                 \
        compute(ic<2*(M) + 1>{});                                             \
        __builtin_amdgcn_s_setprio(0);                                        \
        __builtin_amdgcn_sched_barrier(0);                                    \
    }

    // prologue: S0,S1,S2,S3 then B0,B1 (order pinned)
    stageW(0);
    __builtin_amdgcn_sched_barrier(0);
    stageW(1);
    __builtin_amdgcn_sched_barrier(0);
    stageW(2);
    __builtin_amdgcn_sched_barrier(0);
    stageW(3);
    __builtin_amdgcn_sched_barrier(0);
    loadB(ic<0>{});
    loadB(ic<1>{});
    __builtin_amdgcn_sched_barrier(0);

    if constexpr (MODE == 0) {
        PITER2(0, 16)  PITER2(1, 20)  PITER2(2, 20)  PITER2(3, 24)
        PITER2(4, 28)  PITER2(5, 24)
        epiH(b1);
        PITER2(6, 16)  PITER2(7, 8)
        epiH(b2);
        PITER2(8, 4)   PITER2(9, 0)
    } else {
        PITER2(0, 16)  PITER2(1, 20)  PITER2(2, 20)  PITER2(3, 16)
        epiH(b1);
        PITER2(4, 12)  PITER2(5, 8)
        epiH(b2);
        PITER2(6, 4)   PITER2(7, 0)
    }
#undef PITER2

    // ================= bias3 + LayerNorm + residual (+ ybuf) =================
    float vsum = 0.f, vsq = 0.f;
    #pragma unroll
    for (int nt = 0; nt < 4; ++nt) {
        #pragma unroll
        for (int rq = 0; rq < 4; ++rq) {
            f32x4 bv = *(const f32x4*)(b3 + nt * 32 + rq * 8 + hi * 4);
            #pragma unroll
            for (int j = 0; j < 4; ++j) {
                float v = acc[nt][rq * 4 + j] + bv[j];
                acc[nt][rq * 4 + j] = v;
                vsum += v; vsq += v * v;
            }
        }
    }
    vsum += __shfl_xor(vsum, 32);
    vsq  += __shfl_xor(vsq, 32);
    const float mu = vsum * (1.f / DD);
    const float rs = rsqrtf(vsq * (1.f / DD) - mu * mu + LN_EPS);

    if (gm < NROWS) {
        const float* resid = ((MODE == 0) ? edgef : nodef) + (size_t)gm * DD;
        #pragma unroll
        for (int nt = 0; nt < 4; ++nt) {
            #pragma unroll
            for (int rq = 0; rq < 4; ++rq) {
                const int n0 = nt * 32 + rq * 8 + hi * 4;
                f32x4 gv = *(const f32x4*)(gamma + n0);
                f32x4 bv = *(const f32x4*)(beta + n0);
                f32x4 rv = *(const f32x4*)(resid + n0);
                float y[4];
                f32x4 o;
                #pragma unroll
                for (int j = 0; j < 4; ++j) {
                    y[j] = (acc[nt][rq * 4 + j] - mu) * rs * gv[j] + bv[j];
                    o[j] = y[j] + rv[j];
                }
                *(f32x4*)(outp + (size_t)gm * DD + n0) = o;
                if (MODE == 0) {
                    unsigned long long pkd =
                        (unsigned long long)pk2(y[0], y[1])
                      | ((unsigned long long)pk2(y[2], y[3]) << 32);
                    *(unsigned long long*)((char*)ybuf + (size_t)prow * 256 + n0 * 2) = pkd;
                }
            }
        }
    }
}

extern "C" void kernel_launch(void* const* d_in, const int* in_sizes, int n_in,
                              void* d_out, int out_size, void* d_ws, size_t ws_size,
                              hipStream_t stream) {
    const float* nodef = (const float*)d_in[0];
    const float* edgef = (const float*)d_in[1];
    const int* senders   = (const int*)d_in[2];
    const int* receivers = (const int*)d_in[3];
    const float* We1 = (const float*)d_in[4],  *be1 = (const float*)d_in[5];
    const float* We2 = (const float*)d_in[6],  *be2 = (const float*)d_in[7];
    const float* We3 = (const float*)d_in[8],  *be3 = (const float*)d_in[9];
    const float* ge  = (const float*)d_in[10], *bege = (const float*)d_in[11];
    const float* Wn1 = (const float*)d_in[12], *bn1 = (const float*)d_in[13];
    const float* Wn2 = (const float*)d_in[14], *bn2 = (const float*)d_in[15];
    const float* Wn3 = (const float*)d_in[16], *bn3 = (const float*)d_in[17];
    const float* gn  = (const float*)d_in[18], *begn = (const float*)d_in[19];

    float* out_node = (float*)d_out;
    float* out_edge = (float*)d_out + (size_t)NNODES * DD;

    char* ws = (char*)d_ws;
    size_t o = 0;
    unsigned short* aggb = (unsigned short*)(ws + o); o += (size_t)NNODES * 256;
    unsigned* ybuf = (unsigned*)(ws + o);             o += (size_t)NEDGES * 256;
    unsigned short* nodb = (unsigned short*)(ws + o); o += (size_t)NNODES * 256;
    char* img_e = ws + o;           o += 20 * 8192;
    char* img_n = ws + o;           o += 16 * 8192;
    int* cnt    = (int*)(ws + o);   o += NNODES * 4;
    int* cursor = (int*)(ws + o);   o += NNODES * 4;
    int* off    = (int*)(ws + o);   o += (NNODES + 4) * 4;
    int* perm   = (int*)(ws + o);   o += NEDGES * 4;

    hipMemsetAsync(cnt, 0, NNODES * 4, stream);
    prepass<<<72 + 1024, NTH, 0, stream>>>(We1, We2, We3, Wn1, Wn2, Wn3,
                                           img_e, img_n,
                                           nodef, receivers, (uint4*)nodb, cnt);
    csr_scan<<<1, 1024, 0, stream>>>(cnt, off, cursor);
    csr_fill<<<(NEDGES + NTH - 1) / NTH, NTH, 0, stream>>>(receivers, cursor, perm);

    mgn_mfma<0><<<dim3((NEDGES + 127) / 128), dim3(NTH), 0, stream>>>(
        nodef, edgef, nodb, senders, receivers, perm, img_e,
        be1, be2, be3, ge, bege, aggb, ybuf, out_edge);

    aggregate<<<(NNODES + 3) / 4, NTH, 0, stream>>>(ybuf, off, (unsigned*)aggb);

    mgn_mfma<1><<<dim3((NNODES + 127) / 128), dim3(NTH), 0, stream>>>(
        nodef, edgef, nodb, senders, receivers, perm, img_n,
        bn1, bn2, bn3, gn, begn, aggb, ybuf, out_node);
}

// Round 16
// 323.932 us; speedup vs baseline: 1.2202x; 1.0050x over previous
//
#include <hip/hip_runtime.h>

#define NNODES 50000
#define NEDGES 200000
#define DD 128
#define LN_EPS 1e-5f
#define NTH 256

typedef __attribute__((ext_vector_type(8))) short bf16x8;
typedef __attribute__((ext_vector_type(4))) float f32x4;
typedef __attribute__((ext_vector_type(16))) float f32x16;

template<int N> struct ic { static constexpr int value = N; };

__device__ __forceinline__ unsigned short bfr(float f) {
    union { float f; unsigned u; } v; v.f = f;
    return (unsigned short)((v.u + 0x7fffu + ((v.u >> 16) & 1u)) >> 16);
}
__device__ __forceinline__ unsigned pk2(float a, float b) {
    return (unsigned)bfr(a) | ((unsigned)bfr(b) << 16);
}
__device__ __forceinline__ void gload_lds16(const void* g, void* l) {
    __builtin_amdgcn_global_load_lds(
        (const __attribute__((address_space(1))) void*)g,
        (__attribute__((address_space(3))) void*)l, 16, 0, 0);
}

// ---------------------------------------------------------------------------
// Fused pre-pass: blocks [0,72)  -> weight image builder (r6-proven layout)
//                 blocks [72, +1024) -> nodef bf16 mirror + receiver histogram
// ---------------------------------------------------------------------------
__global__ __launch_bounds__(NTH)
void prepass(const float* __restrict__ We1, const float* __restrict__ We2,
             const float* __restrict__ We3, const float* __restrict__ Wn1,
             const float* __restrict__ Wn2, const float* __restrict__ Wn3,
             char* __restrict__ img_e, char* __restrict__ img_n,
             const float* __restrict__ nodef, const int* __restrict__ recv,
             uint4* __restrict__ nodb, int* __restrict__ cnt) {
    if (blockIdx.x < 72) {
        int tid = blockIdx.x * NTH + threadIdx.x;
        const float* W; char* dst; int q;
        if      (tid <  6144) { W = We1; dst = img_e;             q = tid;         }
        else if (tid <  8192) { W = We2; dst = img_e + 12 * 8192; q = tid - 6144;  }
        else if (tid < 10240) { W = We3; dst = img_e + 16 * 8192; q = tid - 8192;  }
        else if (tid < 14336) { W = Wn1; dst = img_n;             q = tid - 10240; }
        else if (tid < 16384) { W = Wn2; dst = img_n + 8 * 8192;  q = tid - 14336; }
        else if (tid < 18432) { W = Wn3; dst = img_n + 12 * 8192; q = tid - 16384; }
        else return;
        int c = q >> 9, rem = q & 511;
        int nt = rem >> 7, r2 = rem & 127, n32 = r2 >> 2, ks = r2 & 3;
        int n = nt * 32 + n32;
        int sx = (n32 + (n32 >> 2)) & 3;
        int k0 = c * 32 + ks * 8;
        unsigned short o[8];
        #pragma unroll
        for (int e = 0; e < 8; ++e)
            o[e] = bfr(W[(size_t)(k0 + e) * DD + n]);
        uint4 val;
        val.x = (unsigned)o[0] | ((unsigned)o[1] << 16);
        val.y = (unsigned)o[2] | ((unsigned)o[3] << 16);
        val.z = (unsigned)o[4] | ((unsigned)o[5] << 16);
        val.w = (unsigned)o[6] | ((unsigned)o[7] << 16);
        *(uint4*)(dst + (size_t)c * 8192 + nt * 2048 + n32 * 64 + ((ks ^ sx) << 4)) = val;
    } else {
        const int b = blockIdx.x - 72;
        const int tid0 = b * NTH + threadIdx.x;
        if (tid0 < NEDGES) atomicAdd(&cnt[recv[tid0]], 1);
        const int NG = NNODES * 16;
        for (int g = tid0; g < NG; g += 1024 * NTH) {
            f32x4 a = ((const f32x4*)nodef)[g * 2];
            f32x4 bb = ((const f32x4*)nodef)[g * 2 + 1];
            uint4 o;
            o.x = pk2(a[0], a[1]); o.y = pk2(a[2], a[3]);
            o.z = pk2(bb[0], bb[1]); o.w = pk2(bb[2], bb[3]);
            nodb[g] = o;
        }
    }
}

// ---------------------------------------------------------------------------
// CSR: single-block scan + fill (stores perm[e])
// ---------------------------------------------------------------------------
__global__ __launch_bounds__(1024)
void csr_scan(const int* __restrict__ cnt, int* __restrict__ off, int* __restrict__ cursor) {
    __shared__ int part[1024];
    const int t = threadIdx.x;
    const int CH = (NNODES + 1023) / 1024;
    const int base = t * CH;
    int s = 0;
    for (int i = 0; i < CH; ++i) {
        int idx = base + i;
        if (idx < NNODES) s += cnt[idx];
    }
    part[t] = s;
    __syncthreads();
    for (int d = 1; d < 1024; d <<= 1) {
        int v = (t >= d) ? part[t - d] : 0;
        __syncthreads();
        part[t] += v;
        __syncthreads();
    }
    int run = (t == 0) ? 0 : part[t - 1];
    for (int i = 0; i < CH; ++i) {
        int idx = base + i;
        if (idx < NNODES) {
            off[idx] = run; cursor[idx] = run;
            run += cnt[idx];
        }
    }
    if (t == 1023) off[NNODES] = NEDGES;
}

__global__ void csr_fill(const int* __restrict__ recv, int* __restrict__ cursor,
                         int* __restrict__ perm) {
    int e = blockIdx.x * NTH + threadIdx.x;
    if (e < NEDGES) {
        int p = atomicAdd(&cursor[recv[e]], 1);
        perm[e] = p;
    }
}

// ---------------------------------------------------------------------------
// Aggregate (bf16): ybuf is CSR-ordered -> pure streaming reads.
// ---------------------------------------------------------------------------
__global__ __launch_bounds__(NTH)
void aggregate(const unsigned* __restrict__ ybuf,
               const int* __restrict__ off,
               unsigned* __restrict__ aggb) {
    const int n = blockIdx.x * 4 + (threadIdx.x >> 6);
    const int l = threadIdx.x & 63;
    if (n >= NNODES) return;
    const int j0 = off[n], j1 = off[n + 1];
    float sx = 0.f, sy = 0.f;
    int j = j0;
    for (; j + 4 <= j1; j += 4) {
        unsigned v0 = ybuf[(size_t)j * 64 + l];
        unsigned v1 = ybuf[(size_t)(j + 1) * 64 + l];
        unsigned v2 = ybuf[(size_t)(j + 2) * 64 + l];
        unsigned v3 = ybuf[(size_t)(j + 3) * 64 + l];
        sx += __uint_as_float(v0 << 16) + __uint_as_float(v1 << 16)
            + __uint_as_float(v2 << 16) + __uint_as_float(v3 << 16);
        sy += __uint_as_float(v0 & 0xffff0000u) + __uint_as_float(v1 & 0xffff0000u)
            + __uint_as_float(v2 & 0xffff0000u) + __uint_as_float(v3 & 0xffff0000u);
    }
    for (; j < j1; ++j) {
        unsigned v = ybuf[(size_t)j * 64 + l];
        sx += __uint_as_float(v << 16);
        sy += __uint_as_float(v & 0xffff0000u);
    }
    aggb[(size_t)n * 64 + l] = pk2(sx, sy);
}

// ---------------------------------------------------------------------------
// Fused MLP, 32x32x16 MFMA (r12 structure; NEW: accumulator split by chunk
// parity -> 8 independent MFMA dependency chains per wave instead of 4.
// Even chunks -> acc, odd chunks -> acc2; folded at each epilogue.
// Compute order per macro-iter: (2M,kh0) (2M+1,kh0) (2M,kh1) (2M+1,kh1) --
// dependent MFMAs are >= 8 issue slots apart.
// vmcnt tables identical to r12 (compute order adds no vmem ops).
// ---------------------------------------------------------------------------
template<int MODE>
__global__ __launch_bounds__(NTH, 2)
void mgn_mfma(const float* __restrict__ nodef, const float* __restrict__ edgef,
              const unsigned short* __restrict__ nodb,
              const int* __restrict__ senders, const int* __restrict__ receivers,
              const int* __restrict__ perm,
              const char* __restrict__ img,
              const float* __restrict__ b1, const float* __restrict__ b2,
              const float* __restrict__ b3,
              const float* __restrict__ gamma, const float* __restrict__ beta,
              const unsigned short* __restrict__ aggb, unsigned* __restrict__ ybuf,
              float* __restrict__ outp)
{
    __shared__ char Wbuf[6 * 8192];   // 6 rotating k32 weight chunks (3 pairs)
    __shared__ char Hb[4 * 8192];     // per-wave 32 rows x 128 k bf16, swizzled

    const int t  = threadIdx.x;
    const int w  = t >> 6;
    const int l  = t & 63;
    const int ln = l & 31;
    const int hi = l >> 5;
    const int row0 = blockIdx.x * 128;
    const int gm = row0 + w * 32 + ln;
    constexpr int NROWS = (MODE == 0) ? NEDGES : NNODES;
    constexpr int NK1   = (MODE == 0) ? 12 : 8;
    constexpr int NCH   = NK1 + 8;
    const int gmc = gm < NROWS ? gm : NROWS - 1;
    const int sxA = (ln + (ln >> 2)) & 3;
    const int sxH = ln & 15;

    int srow = 0, rrow = 0, prow = 0;
    if (MODE == 0) { srow = senders[gmc]; rrow = receivers[gmc]; prow = perm[gmc]; }

    const f32x16 fz = {0.f,0.f,0.f,0.f,0.f,0.f,0.f,0.f,
                       0.f,0.f,0.f,0.f,0.f,0.f,0.f,0.f};
    f32x16 acc[4];    // even chunks
    f32x16 acc2[4];   // odd chunks
    #pragma unroll
    for (int nt = 0; nt < 4; ++nt) { acc[nt] = fz; acc2[nt] = fz; }

    bf16x8 bS[4][2];   // bf16 B ring (4 chunk slots)
    f32x4  fS[4][4];   // fp32 B ring (edge chunks 8..11)

    auto stageW = [&](int c) {
        const char* src = img + (size_t)c * 8192 + t * 16;
        char* dstl = Wbuf + (c % 6) * 8192 + t * 16;
        gload_lds16(src, dstl);
        gload_lds16(src + 4096, dstl + 4096);
    };

    auto loadBB = [&](auto CC, bf16x8* dst) {
        constexpr int c = decltype(CC)::value;
        const unsigned short* base;
        if constexpr (MODE == 0) {
            base = (c < 4) ? nodb + (size_t)srow * DD : nodb + (size_t)rrow * DD;
        } else {
            base = (c < 4) ? nodb + (size_t)gmc * DD : aggb + (size_t)gmc * DD;
        }
        const char* p = (const char*)base + (c & 3) * 64 + hi * 16;
        dst[0] = *(const bf16x8*)p;
        dst[1] = *(const bf16x8*)(p + 32);
    };

    auto loadBF = [&](auto CC, f32x4* dst) {
        constexpr int c = decltype(CC)::value;
        const float* p = edgef + (size_t)gmc * DD + (c & 3) * 32 + hi * 8;
        dst[0] = *(const f32x4*)p;
        dst[1] = *(const f32x4*)(p + 4);
        dst[2] = *(const f32x4*)(p + 16);
        dst[3] = *(const f32x4*)(p + 20);
    };

    auto cvtB = [&](const f32x4* br) {
        union { unsigned u[4]; bf16x8 v; } r;
        r.u[0] = pk2(br[0][0], br[0][1]);
        r.u[1] = pk2(br[0][2], br[0][3]);
        r.u[2] = pk2(br[1][0], br[1][1]);
        r.u[3] = pk2(br[1][2], br[1][3]);
        return r.v;
    };

    auto loadBH = [&](int ks, int kh) {
        const char* p = Hb + w * 8192 + ln * 256
                      + (((ks * 4 + kh * 2 + hi) ^ sxH) << 4);
        return *(const bf16x8*)p;
    };

    auto getB = [&](auto CC, int kh) -> bf16x8 {
        constexpr int c = decltype(CC)::value;
        if constexpr (c >= NK1) {
            return loadBH((c - NK1) & 3, kh);
        } else if constexpr (MODE == 0 && c >= 8) {
            return cvtB(&fS[c & 3][kh * 2]);
        } else {
            return bS[c & 3][kh];
        }
    };

    // one (chunk, kh) quartet of MFMAs into the given accumulator bank
    auto computeK = [&](auto CC, int kh, f32x16* ac) {
        constexpr int c = decltype(CC)::value;
        const char* bp = Wbuf + (c % 6) * 8192 + ln * 64;
        bf16x8 b = getB(CC, kh);
        #pragma unroll
        for (int nt = 0; nt < 4; ++nt) {
            bf16x8 a = *(const bf16x8*)(bp + nt * 2048
                        + (((kh * 2 + hi) ^ sxA) << 4));
            ac[nt] = __builtin_amdgcn_mfma_f32_32x32x16_bf16(a, b, ac[nt], 0, 0, 0);
        }
    };

    auto epiH = [&](const float* bias) {
        #pragma unroll
        for (int nt = 0; nt < 4; ++nt) {
            #pragma unroll
            for (int rq = 0; rq < 4; ++rq) {
                f32x4 bv = *(const f32x4*)(bias + nt * 32 + rq * 8 + hi * 4);
                unsigned short h[4];
                #pragma unroll
                for (int j = 0; j < 4; ++j)
                    h[j] = bfr(fmaxf(acc[nt][rq * 4 + j] + acc2[nt][rq * 4 + j]
                                     + bv[j], 0.f));
                char* p = Hb + w * 8192 + ln * 256
                        + (((nt * 4 + rq) ^ sxH) << 4) + hi * 8;
                unsigned lo = (unsigned)h[0] | ((unsigned)h[1] << 16);
                unsigned hx = (unsigned)h[2] | ((unsigned)h[3] << 16);
                *(unsigned long long*)p =
                    (unsigned long long)lo | ((unsigned long long)hx << 32);
            }
            acc[nt] = fz;
            acc2[nt] = fz;
        }
    };

    auto loadB = [&](auto CC) {
        constexpr int c = decltype(CC)::value;
        if constexpr (c < NK1) {
            if constexpr (MODE == 0 && c >= 8) loadBF(CC, fS[c & 3]);
            else                               loadBB(CC, bS[c & 3]);
        }
    };

// Macro-iter M: chunks (2M -> acc, 2M+1 -> acc2), kh-interleaved.
#define PITER2(M, VM)                                                         \
    {                                                                         \
        __builtin_amdgcn_s_barrier();                                         \
        __builtin_amdgcn_sched_barrier(0);                                    \
        if constexpr (2*(M) + 4 < NCH) stageW(2*(M) + 4);                     \
        if constexpr (2*(M) + 5 < NCH) stageW(2*(M) + 5);                     \
        __builtin_amdgcn_sched_barrier(0);                                    \
        loadB(ic<2*(M) + 2>{});                                               \
        loadB(ic<2*(M) + 3>{});                                               \
        __builtin_amdgcn_sched_barrier(0);                                    \
        asm volatile("s_waitcnt vmcnt(" #VM ")" ::: "memory");                \
        __builtin_amdgcn_sched_barrier(0);                                    \
        computeK(ic<2*(M)>{},     0, acc);                                    \
        computeK(ic<2*(M) + 1>{}, 0, acc2);                                   \
        computeK(ic<2*(M)>{},     1, acc);                                    \
        computeK(ic<2*(M) + 1>{}, 1, acc2);                                   \
    }

    // prologue: S0,S1,S2,S3 then B0,B1 (order pinned)
    stageW(0);
    __builtin_amdgcn_sched_barrier(0);
    stageW(1);
    __builtin_amdgcn_sched_barrier(0);
    stageW(2);
    __builtin_amdgcn_sched_barrier(0);
    stageW(3);
    __builtin_amdgcn_sched_barrier(0);
    loadB(ic<0>{});
    loadB(ic<1>{});
    __builtin_amdgcn_sched_barrier(0);

    if constexpr (MODE == 0) {
        PITER2(0, 16)  PITER2(1, 20)  PITER2(2, 20)  PITER2(3, 24)
        PITER2(4, 28)  PITER2(5, 24)
        epiH(b1);
        PITER2(6, 16)  PITER2(7, 8)
        epiH(b2);
        PITER2(8, 4)   PITER2(9, 0)
    } else {
        PITER2(0, 16)  PITER2(1, 20)  PITER2(2, 20)  PITER2(3, 16)
        epiH(b1);
        PITER2(4, 12)  PITER2(5, 8)
        epiH(b2);
        PITER2(6, 4)   PITER2(7, 0)
    }
#undef PITER2

    // ================= bias3 + LayerNorm + residual (+ ybuf) =================
    float vsum = 0.f, vsq = 0.f;
    #pragma unroll
    for (int nt = 0; nt < 4; ++nt) {
        #pragma unroll
        for (int rq = 0; rq < 4; ++rq) {
            f32x4 bv = *(const f32x4*)(b3 + nt * 32 + rq * 8 + hi * 4);
            #pragma unroll
            for (int j = 0; j < 4; ++j) {
                float v = acc[nt][rq * 4 + j] + acc2[nt][rq * 4 + j] + bv[j];
                acc[nt][rq * 4 + j] = v;
                vsum += v; vsq += v * v;
            }
        }
    }
    vsum += __shfl_xor(vsum, 32);
    vsq  += __shfl_xor(vsq, 32);
    const float mu = vsum * (1.f / DD);
    const float rs = rsqrtf(vsq * (1.f / DD) - mu * mu + LN_EPS);

    if (gm < NROWS) {
        const float* resid = ((MODE == 0) ? edgef : nodef) + (size_t)gm * DD;
        #pragma unroll
        for (int nt = 0; nt < 4; ++nt) {
            #pragma unroll
            for (int rq = 0; rq < 4; ++rq) {
                const int n0 = nt * 32 + rq * 8 + hi * 4;
                f32x4 gv = *(const f32x4*)(gamma + n0);
                f32x4 bv = *(const f32x4*)(beta + n0);
                f32x4 rv = *(const f32x4*)(resid + n0);
                float y[4];
                f32x4 o;
                #pragma unroll
                for (int j = 0; j < 4; ++j) {
                    y[j] = (acc[nt][rq * 4 + j] - mu) * rs * gv[j] + bv[j];
                    o[j] = y[j] + rv[j];
                }
                *(f32x4*)(outp + (size_t)gm * DD + n0) = o;
                if (MODE == 0) {
                    unsigned long long pkd =
                        (unsigned long long)pk2(y[0], y[1])
                      | ((unsigned long long)pk2(y[2], y[3]) << 32);
                    *(unsigned long long*)((char*)ybuf + (size_t)prow * 256 + n0 * 2) = pkd;
                }
            }
        }
    }
}

extern "C" void kernel_launch(void* const* d_in, const int* in_sizes, int n_in,
                              void* d_out, int out_size, void* d_ws, size_t ws_size,
                              hipStream_t stream) {
    const float* nodef = (const float*)d_in[0];
    const float* edgef = (const float*)d_in[1];
    const int* senders   = (const int*)d_in[2];
    const int* receivers = (const int*)d_in[3];
    const float* We1 = (const float*)d_in[4],  *be1 = (const float*)d_in[5];
    const float* We2 = (const float*)d_in[6],  *be2 = (const float*)d_in[7];
    const float* We3 = (const float*)d_in[8],  *be3 = (const float*)d_in[9];
    const float* ge  = (const float*)d_in[10], *bege = (const float*)d_in[11];
    const float* Wn1 = (const float*)d_in[12], *bn1 = (const float*)d_in[13];
    const float* Wn2 = (const float*)d_in[14], *bn2 = (const float*)d_in[15];
    const float* Wn3 = (const float*)d_in[16], *bn3 = (const float*)d_in[17];
    const float* gn  = (const float*)d_in[18], *begn = (const float*)d_in[19];

    float* out_node = (float*)d_out;
    float* out_edge = (float*)d_out + (size_t)NNODES * DD;

    char* ws = (char*)d_ws;
    size_t o = 0;
    unsigned short* aggb = (unsigned short*)(ws + o); o += (size_t)NNODES * 256;
    unsigned* ybuf = (unsigned*)(ws + o);             o += (size_t)NEDGES * 256;
    unsigned short* nodb = (unsigned short*)(ws + o); o += (size_t)NNODES * 256;
    char* img_e = ws + o;           o += 20 * 8192;
    char* img_n = ws + o;           o += 16 * 8192;
    int* cnt    = (int*)(ws + o);   o += NNODES * 4;
    int* cursor = (int*)(ws + o);   o += NNODES * 4;
    int* off    = (int*)(ws + o);   o += (NNODES + 4) * 4;
    int* perm   = (int*)(ws + o);   o += NEDGES * 4;

    hipMemsetAsync(cnt, 0, NNODES * 4, stream);
    prepass<<<72 + 1024, NTH, 0, stream>>>(We1, We2, We3, Wn1, Wn2, Wn3,
                                           img_e, img_n,
                                           nodef, receivers, (uint4*)nodb, cnt);
    csr_scan<<<1, 1024, 0, stream>>>(cnt, off, cursor);
    csr_fill<<<(NEDGES + NTH - 1) / NTH, NTH, 0, stream>>>(receivers, cursor, perm);

    mgn_mfma<0><<<dim3((NEDGES + 127) / 128), dim3(NTH), 0, stream>>>(
        nodef, edgef, nodb, senders, receivers, perm, img_e,
        be1, be2, be3, ge, bege, aggb, ybuf, out_edge);

    aggregate<<<(NNODES + 3) / 4, NTH, 0, stream>>>(ybuf, off, (unsigned*)aggb);

    mgn_mfma<1><<<dim3((NNODES + 127) / 128), dim3(NTH), 0, stream>>>(
        nodef, edgef, nodb, senders, receivers, perm, img_n,
        bn1, bn2, bn3, gn, begn, aggb, ybuf, out_node);
}

// Round 18
// 301.780 us; speedup vs baseline: 1.3098x; 1.0734x over previous
//
#include <hip/hip_runtime.h>

#define NNODES 50000
#define NEDGES 200000
#define DD 128
#define LN_EPS 1e-5f
#define NTH 256

typedef __attribute__((ext_vector_type(8))) short bf16x8;
typedef __attribute__((ext_vector_type(4))) float f32x4;
typedef __attribute__((ext_vector_type(16))) float f32x16;

template<int N> struct ic { static constexpr int value = N; };

__device__ __forceinline__ unsigned short bfr(float f) {
    union { float f; unsigned u; } v; v.f = f;
    return (unsigned short)((v.u + 0x7fffu + ((v.u >> 16) & 1u)) >> 16);
}
__device__ __forceinline__ unsigned pk2(float a, float b) {
    return (unsigned)bfr(a) | ((unsigned)bfr(b) << 16);
}
__device__ __forceinline__ void gload_lds16(const void* g, void* l) {
    __builtin_amdgcn_global_load_lds(
        (const __attribute__((address_space(1))) void*)g,
        (__attribute__((address_space(3))) void*)l, 16, 0, 0);
}

// ---------------------------------------------------------------------------
// Fused pre-pass: blocks [0,72)  -> weight image builder (r6-proven layout)
//                 blocks [72, +1024) -> nodef bf16 mirror + receiver histogram
// ---------------------------------------------------------------------------
__global__ __launch_bounds__(NTH)
void prepass(const float* __restrict__ We1, const float* __restrict__ We2,
             const float* __restrict__ We3, const float* __restrict__ Wn1,
             const float* __restrict__ Wn2, const float* __restrict__ Wn3,
             char* __restrict__ img_e, char* __restrict__ img_n,
             const float* __restrict__ nodef, const int* __restrict__ recv,
             uint4* __restrict__ nodb, int* __restrict__ cnt) {
    if (blockIdx.x < 72) {
        int tid = blockIdx.x * NTH + threadIdx.x;
        const float* W; char* dst; int q;
        if      (tid <  6144) { W = We1; dst = img_e;             q = tid;         }
        else if (tid <  8192) { W = We2; dst = img_e + 12 * 8192; q = tid - 6144;  }
        else if (tid < 10240) { W = We3; dst = img_e + 16 * 8192; q = tid - 8192;  }
        else if (tid < 14336) { W = Wn1; dst = img_n;             q = tid - 10240; }
        else if (tid < 16384) { W = Wn2; dst = img_n + 8 * 8192;  q = tid - 14336; }
        else if (tid < 18432) { W = Wn3; dst = img_n + 12 * 8192; q = tid - 16384; }
        else return;
        int c = q >> 9, rem = q & 511;
        int nt = rem >> 7, r2 = rem & 127, n32 = r2 >> 2, ks = r2 & 3;
        int n = nt * 32 + n32;
        int sx = (n32 + (n32 >> 2)) & 3;
        int k0 = c * 32 + ks * 8;
        unsigned short o[8];
        #pragma unroll
        for (int e = 0; e < 8; ++e)
            o[e] = bfr(W[(size_t)(k0 + e) * DD + n]);
        uint4 val;
        val.x = (unsigned)o[0] | ((unsigned)o[1] << 16);
        val.y = (unsigned)o[2] | ((unsigned)o[3] << 16);
        val.z = (unsigned)o[4] | ((unsigned)o[5] << 16);
        val.w = (unsigned)o[6] | ((unsigned)o[7] << 16);
        *(uint4*)(dst + (size_t)c * 8192 + nt * 2048 + n32 * 64 + ((ks ^ sx) << 4)) = val;
    } else {
        const int b = blockIdx.x - 72;
        const int tid0 = b * NTH + threadIdx.x;
        if (tid0 < NEDGES) atomicAdd(&cnt[recv[tid0]], 1);
        const int NG = NNODES * 16;
        for (int g = tid0; g < NG; g += 1024 * NTH) {
            f32x4 a = ((const f32x4*)nodef)[g * 2];
            f32x4 bb = ((const f32x4*)nodef)[g * 2 + 1];
            uint4 o;
            o.x = pk2(a[0], a[1]); o.y = pk2(a[2], a[3]);
            o.z = pk2(bb[0], bb[1]); o.w = pk2(bb[2], bb[3]);
            nodb[g] = o;
        }
    }
}

// ---------------------------------------------------------------------------
// CSR: 2-level scan (r12-proven). cursor doubles as the live fill cursor
// consumed by the edge kernel's inline atomic slot-claim.
// ---------------------------------------------------------------------------
__global__ __launch_bounds__(NTH)
void csr_scan1(const int* __restrict__ cnt, int* __restrict__ part) {
    __shared__ int red[NTH];
    const int b = blockIdx.x, t = threadIdx.x;
    const int base = b * 196;
    int s = 0;
    for (int i = t; i < 196; i += NTH) {
        int idx = base + i;
        if (idx < NNODES) s += cnt[idx];
    }
    red[t] = s;
    __syncthreads();
    for (int d = NTH / 2; d > 0; d >>= 1) {
        if (t < d) red[t] += red[t + d];
        __syncthreads();
    }
    if (t == 0) part[b] = red[0];
}

__global__ __launch_bounds__(NTH)
void csr_scan2(const int* __restrict__ cnt, const int* __restrict__ part,
               int* __restrict__ off, int* __restrict__ cursor) {
    __shared__ int sp[NTH];
    const int t = threadIdx.x;
    sp[t] = part[t];
    __syncthreads();
    for (int d = 1; d < NTH; d <<= 1) {
        int v = (t >= d) ? sp[t - d] : 0;
        __syncthreads();
        sp[t] += v;
        __syncthreads();
    }
    int run = (t == 0) ? 0 : sp[t - 1];
    const int base = t * 196;
    for (int i = 0; i < 196; ++i) {
        int idx = base + i;
        if (idx < NNODES) { off[idx] = run; cursor[idx] = run; run += cnt[idx]; }
    }
    if (t == NTH - 1) off[NNODES] = NEDGES;
}

// ---------------------------------------------------------------------------
// Aggregate (bf16): ybuf is CSR-ordered -> pure streaming reads.
// ---------------------------------------------------------------------------
__global__ __launch_bounds__(NTH)
void aggregate(const unsigned* __restrict__ ybuf,
               const int* __restrict__ off,
               unsigned* __restrict__ aggb) {
    const int n = blockIdx.x * 4 + (threadIdx.x >> 6);
    const int l = threadIdx.x & 63;
    if (n >= NNODES) return;
    const int j0 = off[n], j1 = off[n + 1];
    float sx = 0.f, sy = 0.f;
    int j = j0;
    for (; j + 4 <= j1; j += 4) {
        unsigned v0 = ybuf[(size_t)j * 64 + l];
        unsigned v1 = ybuf[(size_t)(j + 1) * 64 + l];
        unsigned v2 = ybuf[(size_t)(j + 2) * 64 + l];
        unsigned v3 = ybuf[(size_t)(j + 3) * 64 + l];
        sx += __uint_as_float(v0 << 16) + __uint_as_float(v1 << 16)
            + __uint_as_float(v2 << 16) + __uint_as_float(v3 << 16);
        sy += __uint_as_float(v0 & 0xffff0000u) + __uint_as_float(v1 & 0xffff0000u)
            + __uint_as_float(v2 & 0xffff0000u) + __uint_as_float(v3 & 0xffff0000u);
    }
    for (; j < j1; ++j) {
        unsigned v = ybuf[(size_t)j * 64 + l];
        sx += __uint_as_float(v << 16);
        sy += __uint_as_float(v & 0xffff0000u);
    }
    aggb[(size_t)n * 64 + l] = pk2(sx, sy);
}

// ---------------------------------------------------------------------------
// Fused MLP, 32x32x16 MFMA (r12 structure verbatim = best validated config).
// Inline CSR fill FIXED: only the hi==0 lane of each row pair claims the
// slot (atomicAdd), then broadcasts to its hi==1 partner via __shfl(p, ln).
// (r17's bug: both lanes claimed -> 2x slot consumption -> range overflow.)
// ---------------------------------------------------------------------------
template<int MODE>
__global__ __launch_bounds__(NTH, 2)
void mgn_mfma(const float* __restrict__ nodef, const float* __restrict__ edgef,
              const unsigned short* __restrict__ nodb,
              const int* __restrict__ senders, const int* __restrict__ receivers,
              int* __restrict__ cursor,
              const char* __restrict__ img,
              const float* __restrict__ b1, const float* __restrict__ b2,
              const float* __restrict__ b3,
              const float* __restrict__ gamma, const float* __restrict__ beta,
              const unsigned short* __restrict__ aggb, unsigned* __restrict__ ybuf,
              float* __restrict__ outp)
{
    __shared__ char Wbuf[6 * 8192];   // 6 rotating k32 weight chunks (3 pairs)
    __shared__ char Hb[4 * 8192];     // per-wave 32 rows x 128 k bf16, swizzled

    const int t  = threadIdx.x;
    const int w  = t >> 6;
    const int l  = t & 63;
    const int ln = l & 31;
    const int hi = l >> 5;
    const int row0 = blockIdx.x * 128;
    const int gm = row0 + w * 32 + ln;
    constexpr int NROWS = (MODE == 0) ? NEDGES : NNODES;
    constexpr int NK1   = (MODE == 0) ? 12 : 8;
    constexpr int NCH   = NK1 + 8;
    const int gmc = gm < NROWS ? gm : NROWS - 1;
    const int sxA = (ln + (ln >> 2)) & 3;
    const int sxH = ln & 15;

    int srow = 0, rrow = 0, prow = 0;
    if (MODE == 0) {
        srow = senders[gmc]; rrow = receivers[gmc];
        int pclaim = 0;
        if (hi == 0 && gm < NROWS) pclaim = atomicAdd(&cursor[rrow], 1);
        prow = __shfl(pclaim, ln);   // both halves of row gm share one slot
    }

    const f32x16 fz = {0.f,0.f,0.f,0.f,0.f,0.f,0.f,0.f,
                       0.f,0.f,0.f,0.f,0.f,0.f,0.f,0.f};
    f32x16 acc[4];
    #pragma unroll
    for (int nt = 0; nt < 4; ++nt) acc[nt] = fz;

    bf16x8 bS[4][2];   // bf16 B ring (4 chunk slots)
    f32x4  fS[4][4];   // fp32 B ring (edge chunks 8..11)

    auto stageW = [&](int c) {
        const char* src = img + (size_t)c * 8192 + t * 16;
        char* dstl = Wbuf + (c % 6) * 8192 + t * 16;
        gload_lds16(src, dstl);
        gload_lds16(src + 4096, dstl + 4096);
    };

    auto loadBB = [&](auto CC, bf16x8* dst) {
        constexpr int c = decltype(CC)::value;
        const unsigned short* base;
        if constexpr (MODE == 0) {
            base = (c < 4) ? nodb + (size_t)srow * DD : nodb + (size_t)rrow * DD;
        } else {
            base = (c < 4) ? nodb + (size_t)gmc * DD : aggb + (size_t)gmc * DD;
        }
        const char* p = (const char*)base + (c & 3) * 64 + hi * 16;
        dst[0] = *(const bf16x8*)p;
        dst[1] = *(const bf16x8*)(p + 32);
    };

    auto loadBF = [&](auto CC, f32x4* dst) {
        constexpr int c = decltype(CC)::value;
        const float* p = edgef + (size_t)gmc * DD + (c & 3) * 32 + hi * 8;
        dst[0] = *(const f32x4*)p;
        dst[1] = *(const f32x4*)(p + 4);
        dst[2] = *(const f32x4*)(p + 16);
        dst[3] = *(const f32x4*)(p + 20);
    };

    auto cvtB = [&](const f32x4* br) {
        union { unsigned u[4]; bf16x8 v; } r;
        r.u[0] = pk2(br[0][0], br[0][1]);
        r.u[1] = pk2(br[0][2], br[0][3]);
        r.u[2] = pk2(br[1][0], br[1][1]);
        r.u[3] = pk2(br[1][2], br[1][3]);
        return r.v;
    };

    auto loadBH = [&](int ks, int kh) {
        const char* p = Hb + w * 8192 + ln * 256
                      + (((ks * 4 + kh * 2 + hi) ^ sxH) << 4);
        return *(const bf16x8*)p;
    };

    auto getB = [&](auto CC, int kh) -> bf16x8 {
        constexpr int c = decltype(CC)::value;
        if constexpr (c >= NK1) {
            return loadBH((c - NK1) & 3, kh);
        } else if constexpr (MODE == 0 && c >= 8) {
            return cvtB(&fS[c & 3][kh * 2]);
        } else {
            return bS[c & 3][kh];
        }
    };

    auto compute = [&](auto CC) {
        constexpr int c = decltype(CC)::value;
        const char* bp = Wbuf + (c % 6) * 8192 + ln * 64;
        #pragma unroll
        for (int kh = 0; kh < 2; ++kh) {
            bf16x8 b = getB(CC, kh);
            #pragma unroll
            for (int nt = 0; nt < 4; ++nt) {
                bf16x8 a = *(const bf16x8*)(bp + nt * 2048
                            + (((kh * 2 + hi) ^ sxA) << 4));
                acc[nt] = __builtin_amdgcn_mfma_f32_32x32x16_bf16(a, b, acc[nt], 0, 0, 0);
            }
        }
    };

    auto epiH = [&](const float* bias) {
        #pragma unroll
        for (int nt = 0; nt < 4; ++nt) {
            #pragma unroll
            for (int rq = 0; rq < 4; ++rq) {
                f32x4 bv = *(const f32x4*)(bias + nt * 32 + rq * 8 + hi * 4);
                unsigned short h[4];
                #pragma unroll
                for (int j = 0; j < 4; ++j)
                    h[j] = bfr(fmaxf(acc[nt][rq * 4 + j] + bv[j], 0.f));
                char* p = Hb + w * 8192 + ln * 256
                        + (((nt * 4 + rq) ^ sxH) << 4) + hi * 8;
                unsigned lo = (unsigned)h[0] | ((unsigned)h[1] << 16);
                unsigned hx = (unsigned)h[2] | ((unsigned)h[3] << 16);
                *(unsigned long long*)p =
                    (unsigned long long)lo | ((unsigned long long)hx << 32);
            }
            acc[nt] = fz;
        }
    };

    auto loadB = [&](auto CC) {
        constexpr int c = decltype(CC)::value;
        if constexpr (c < NK1) {
            if constexpr (MODE == 0 && c >= 8) loadBF(CC, fS[c & 3]);
            else                               loadBB(CC, bS[c & 3]);
        }
    };

// Macro-iter M: chunks (2M, 2M+1). barrier -> stage pair (2M+4,2M+5) ->
// B pair (2M+2,2M+3) -> counted vmcnt -> compute pair.  (r12 verbatim)
#define PITER2(M, VM)                                                         \
    {                                                                         \
        __builtin_amdgcn_s_barrier();                                         \
        __builtin_amdgcn_sched_barrier(0);                                    \
        if constexpr (2*(M) + 4 < NCH) stageW(2*(M) + 4);                     \
        if constexpr (2*(M) + 5 < NCH) stageW(2*(M) + 5);                     \
        __builtin_amdgcn_sched_barrier(0);                                    \
        loadB(ic<2*(M) + 2>{});                                               \
        loadB(ic<2*(M) + 3>{});                                               \
        __builtin_amdgcn_sched_barrier(0);                                    \
        asm volatile("s_waitcnt vmcnt(" #VM ")" ::: "memory");                \
        __builtin_amdgcn_sched_barrier(0);                                    \
        compute(ic<2*(M)>{});                                                 \
        compute(ic<2*(M) + 1>{});                                             \
    }

    // prologue: S0,S1,S2,S3 then B0,B1 (order pinned)
    stageW(0);
    __builtin_amdgcn_sched_barrier(0);
    stageW(1);
    __builtin_amdgcn_sched_barrier(0);
    stageW(2);
    __builtin_amdgcn_sched_barrier(0);
    stageW(3);
    __builtin_amdgcn_sched_barrier(0);
    loadB(ic<0>{});
    loadB(ic<1>{});
    __builtin_amdgcn_sched_barrier(0);

    if constexpr (MODE == 0) {
        PITER2(0, 16)  PITER2(1, 20)  PITER2(2, 20)  PITER2(3, 24)
        PITER2(4, 28)  PITER2(5, 24)
        epiH(b1);
        PITER2(6, 16)  PITER2(7, 8)
        epiH(b2);
        PITER2(8, 4)   PITER2(9, 0)
    } else {
        PITER2(0, 16)  PITER2(1, 20)  PITER2(2, 20)  PITER2(3, 16)
        epiH(b1);
        PITER2(4, 12)  PITER2(5, 8)
        epiH(b2);
        PITER2(6, 4)   PITER2(7, 0)
    }
#undef PITER2

    // ================= bias3 + LayerNorm + residual (+ ybuf) =================
    float vsum = 0.f, vsq = 0.f;
    #pragma unroll
    for (int nt = 0; nt < 4; ++nt) {
        #pragma unroll
        for (int rq = 0; rq < 4; ++rq) {
            f32x4 bv = *(const f32x4*)(b3 + nt * 32 + rq * 8 + hi * 4);
            #pragma unroll
            for (int j = 0; j < 4; ++j) {
                float v = acc[nt][rq * 4 + j] + bv[j];
                acc[nt][rq * 4 + j] = v;
                vsum += v; vsq += v * v;
            }
        }
    }
    vsum += __shfl_xor(vsum, 32);
    vsq  += __shfl_xor(vsq, 32);
    const float mu = vsum * (1.f / DD);
    const float rs = rsqrtf(vsq * (1.f / DD) - mu * mu + LN_EPS);

    if (gm < NROWS) {
        const float* resid = ((MODE == 0) ? edgef : nodef) + (size_t)gm * DD;
        #pragma unroll
        for (int nt = 0; nt < 4; ++nt) {
            #pragma unroll
            for (int rq = 0; rq < 4; ++rq) {
                const int n0 = nt * 32 + rq * 8 + hi * 4;
                f32x4 gv = *(const f32x4*)(gamma + n0);
                f32x4 bv = *(const f32x4*)(beta + n0);
                f32x4 rv = *(const f32x4*)(resid + n0);
                float y[4];
                f32x4 o;
                #pragma unroll
                for (int j = 0; j < 4; ++j) {
                    y[j] = (acc[nt][rq * 4 + j] - mu) * rs * gv[j] + bv[j];
                    o[j] = y[j] + rv[j];
                }
                *(f32x4*)(outp + (size_t)gm * DD + n0) = o;
                if (MODE == 0) {
                    unsigned long long pkd =
                        (unsigned long long)pk2(y[0], y[1])
                      | ((unsigned long long)pk2(y[2], y[3]) << 32);
                    *(unsigned long long*)((char*)ybuf + (size_t)prow * 256 + n0 * 2) = pkd;
                }
            }
        }
    }
}

extern "C" void kernel_launch(void* const* d_in, const int* in_sizes, int n_in,
                              void* d_out, int out_size, void* d_ws, size_t ws_size,
                              hipStream_t stream) {
    const float* nodef = (const float*)d_in[0];
    const float* edgef = (const float*)d_in[1];
    const int* senders   = (const int*)d_in[2];
    const int* receivers = (const int*)d_in[3];
    const float* We1 = (const float*)d_in[4],  *be1 = (const float*)d_in[5];
    const float* We2 = (const float*)d_in[6],  *be2 = (const float*)d_in[7];
    const float* We3 = (const float*)d_in[8],  *be3 = (const float*)d_in[9];
    const float* ge  = (const float*)d_in[10], *bege = (const float*)d_in[11];
    const float* Wn1 = (const float*)d_in[12], *bn1 = (const float*)d_in[13];
    const float* Wn2 = (const float*)d_in[14], *bn2 = (const float*)d_in[15];
    const float* Wn3 = (const float*)d_in[16], *bn3 = (const float*)d_in[17];
    const float* gn  = (const float*)d_in[18], *begn = (const float*)d_in[19];

    float* out_node = (float*)d_out;
    float* out_edge = (float*)d_out + (size_t)NNODES * DD;

    char* ws = (char*)d_ws;
    size_t o = 0;
    unsigned short* aggb = (unsigned short*)(ws + o); o += (size_t)NNODES * 256;
    unsigned* ybuf = (unsigned*)(ws + o);             o += (size_t)NEDGES * 256;
    unsigned short* nodb = (unsigned short*)(ws + o); o += (size_t)NNODES * 256;
    char* img_e = ws + o;           o += 20 * 8192;
    char* img_n = ws + o;           o += 16 * 8192;
    int* cnt    = (int*)(ws + o);   o += NNODES * 4;
    int* cursor = (int*)(ws + o);   o += NNODES * 4;
    int* off    = (int*)(ws + o);   o += (NNODES + 4) * 4;
    int* part   = (int*)(ws + o);   o += NTH * 4;

    hipMemsetAsync(cnt, 0, NNODES * 4, stream);
    prepass<<<72 + 1024, NTH, 0, stream>>>(We1, We2, We3, Wn1, Wn2, Wn3,
                                           img_e, img_n,
                                           nodef, receivers, (uint4*)nodb, cnt);
    csr_scan1<<<NTH, NTH, 0, stream>>>(cnt, part);
    csr_scan2<<<1, NTH, 0, stream>>>(cnt, part, off, cursor);

    mgn_mfma<0><<<dim3((NEDGES + 127) / 128), dim3(NTH), 0, stream>>>(
        nodef, edgef, nodb, senders, receivers, cursor, img_e,
        be1, be2, be3, ge, bege, aggb, ybuf, out_edge);

    aggregate<<<(NNODES + 3) / 4, NTH, 0, stream>>>(ybuf, off, (unsigned*)aggb);

    mgn_mfma<1><<<dim3((NNODES + 127) / 128), dim3(NTH), 0, stream>>>(
        nodef, edgef, nodb, senders, receivers, cursor, img_n,
        bn1, bn2, bn3, gn, begn, aggb, ybuf, out_node);
}